// Round 7
// baseline (700.204 us; speedup 1.0000x reference)
//
#include <hip/hip_runtime.h>
#include <hip/hip_bf16.h>

#define N_NODES 100000
#define NFEAT 9
#define HID 128
#define B_GRAPHS 64
#define SEQ_LEN 768
#define HD 256
#define L_LAYERS 4
#define LN_EPS 1e-5f

typedef __attribute__((ext_vector_type(8))) short short8;
typedef __attribute__((ext_vector_type(4))) float f32x4;

__device__ __forceinline__ float lrelu(float v) { return v > 0.f ? v : 0.2f * v; }

__device__ __forceinline__ float wave_sum64(float x) {
#pragma unroll
  for (int o = 32; o >= 1; o >>= 1) x += __shfl_xor(x, o, 64);
  return x;
}

__device__ __forceinline__ unsigned short bf16r(float v) {
  unsigned int u = __float_as_uint(v);
  return (unsigned short)((u + 0x7fffu + ((u >> 16) & 1u)) >> 16);
}
// pack: low16 = bf16(lo), high16 = bf16(hi)
__device__ __forceinline__ unsigned int bf16pair(float lo, float hi) {
  unsigned int ul = __float_as_uint(lo);
  unsigned int uh = __float_as_uint(hi);
  ul = (ul + 0x7fffu + ((ul >> 16) & 1u)) >> 16;
  uh = (uh + 0x7fffu + ((uh >> 16) & 1u)) & 0xffff0000u;
  return ul | uh;
}

// h = relu(x @ ne_W.T + ne_b); also emits bf16 copy
__global__ __launch_bounds__(256) void ne_kernel(const float* __restrict__ x,
                                                 const float* __restrict__ W,
                                                 const float* __restrict__ b,
                                                 float* __restrict__ h,
                                                 unsigned short* __restrict__ hb) {
  int idx = blockIdx.x * 256 + threadIdx.x;
  int n = idx >> 7, c = idx & 127;
  const float* xr = x + n * NFEAT;
  const float* wr = W + c * NFEAT;
  float acc = b[c];
#pragma unroll
  for (int k = 0; k < NFEAT; ++k) acc += xr[k] * wr[k];
  acc = fmaxf(acc, 0.f);
  h[idx] = acc;
  hb[idx] = bf16r(acc);
}

// convert all L layers of gat_W to bf16
__global__ __launch_bounds__(256) void wcvt_kernel(const float* __restrict__ W,
                                                   unsigned short* __restrict__ wb) {
  int idx = blockIdx.x * 256 + threadIdx.x;
  if (idx < L_LAYERS * HID * HID) wb[idx] = bf16r(W[idx]);
}

__global__ __launch_bounds__(256) void hist_kernel(const int* __restrict__ dst,
                                                   int* __restrict__ cnt, int E) {
  int i = blockIdx.x * 256 + threadIdx.x;
  if (i < E) atomicAdd(&cnt[dst[i]], 1);
}

// hierarchical exclusive scan
__global__ __launch_bounds__(1024) void scan1_kernel(const int* __restrict__ cnt,
                                                     int* __restrict__ off,
                                                     int* __restrict__ bsum, int n) {
  __shared__ int ws[16];
  __shared__ int wx[16];
  int tid = threadIdx.x, lane = tid & 63, w = tid >> 6;
  int i = blockIdx.x * 1024 + tid;
  int v = (i < n) ? cnt[i] : 0;
  int x = v;
#pragma unroll
  for (int o = 1; o < 64; o <<= 1) {
    int t = __shfl_up(x, o, 64);
    if (lane >= o) x += t;
  }
  if (lane == 63) ws[w] = x;
  __syncthreads();
  if (tid == 0) {
    int r = 0;
#pragma unroll
    for (int j = 0; j < 16; ++j) { int t = ws[j]; wx[j] = r; r += t; }
    bsum[blockIdx.x] = r;
  }
  __syncthreads();
  if (i < n) off[i] = wx[w] + x - v;
}

__global__ void scan2_kernel(int* __restrict__ bsum, int nb) {
  int lane = threadIdx.x;
  int i0 = lane * 2, i1 = i0 + 1;
  int a = (i0 < nb) ? bsum[i0] : 0;
  int b = (i1 < nb) ? bsum[i1] : 0;
  int s = a + b, x = s;
#pragma unroll
  for (int o = 1; o < 64; o <<= 1) {
    int t = __shfl_up(x, o, 64);
    if (lane >= o) x += t;
  }
  int excl = x - s;
  if (i0 < nb) bsum[i0] = excl;
  if (i1 < nb) bsum[i1] = excl + a;
}

__global__ __launch_bounds__(256) void scan3_kernel(const int* __restrict__ bsum,
                                                    int* __restrict__ off, int n, int total) {
  int i = blockIdx.x * 256 + threadIdx.x;
  if (i < n) off[i] += bsum[i >> 10];
  else if (i == n) off[i] = total;
}

__global__ __launch_bounds__(256) void scatter_kernel(const int* __restrict__ src,
                                                      const int* __restrict__ dst,
                                                      const int* __restrict__ off,
                                                      int* __restrict__ cur,
                                                      int* __restrict__ eadj, int E) {
  int i = blockIdx.x * 256 + threadIdx.x;
  if (i < E) {
    int d = dst[i];
    int pos = atomicAdd(&cur[d], 1);
    eadj[off[d] + pos] = src[i];
  }
}

// per-edge softmax weights; dst recovered by binary search in off
__global__ __launch_bounds__(256) void edgew_kernel(const int* __restrict__ eadj,
                                                    const int* __restrict__ off,
                                                    const float* __restrict__ esrc,
                                                    const float* __restrict__ edst,
                                                    float4* __restrict__ qw, int E) {
  int j = blockIdx.x * 256 + threadIdx.x;
  if (j >= E) return;
  int s = eadj[j];
  int lo = 0, hi = N_NODES;  // invariant: off[lo] <= j < off[hi]
  while (lo + 1 < hi) {
    int mid = (lo + hi) >> 1;
    if (off[mid] <= j) lo = mid; else hi = mid;
  }
  const float4 es = *(const float4*)(esrc + (size_t)s * 4);
  const float4 ed = *(const float4*)(edst + (size_t)lo * 4);
  float4 q;
  q.x = __expf(lrelu(es.x + ed.x));
  q.y = __expf(lrelu(es.y + ed.y));
  q.z = __expf(lrelu(es.z + ed.z));
  q.w = __expf(lrelu(es.w + ed.w));
  qw[j] = q;
}

// xl = h @ W.T via bf16 MFMA. 128 rows/block, 4 waves (32 rows each), full 128 cols.
// Emits packed bf16 pairs xlp and fp32 logits esrc/edst.
__global__ __launch_bounds__(256) void gat_xl_kernel(const unsigned short* __restrict__ hb,
                                                     const unsigned short* __restrict__ wb,
                                                     const float* __restrict__ asrc,
                                                     const float* __restrict__ adst,
                                                     unsigned int* __restrict__ xlp,
                                                     float* __restrict__ esrc,
                                                     float* __restrict__ edst) {
  __shared__ unsigned short Wl[128][136];  // +8 pad: 2-way bank alias only
  const int tid = threadIdx.x;
  const int lane = tid & 63;
  const int wv = tid >> 6;
  const int base = blockIdx.x * 128;
  const int l15 = lane & 15;
  const int lg = lane >> 4;  // 0..3

  // stage W (bf16) into LDS
#pragma unroll
  for (int t = 0; t < 8; ++t) {
    int f8 = tid + t * 256;          // 2048 chunks of 8 ushorts
    int row = f8 >> 4, c8 = (f8 & 15) * 8;
    uint4 v = *(const uint4*)(wb + row * HID + c8);
    *(uint4*)&Wl[row][c8] = v;
  }
  __syncthreads();

  f32x4 acc[2][8];
#pragma unroll
  for (int rb = 0; rb < 2; ++rb)
#pragma unroll
    for (int nb = 0; nb < 8; ++nb) acc[rb][nb] = (f32x4){0.f, 0.f, 0.f, 0.f};

  int n0 = base + wv * 32 + l15;
  int n1 = n0 + 16;
  if (n0 >= N_NODES) n0 = N_NODES - 1;
  if (n1 >= N_NODES) n1 = N_NODES - 1;
  const size_t rowA0 = (size_t)n0 * HID;
  const size_t rowA1 = (size_t)n1 * HID;

#pragma unroll
  for (int kc = 0; kc < 4; ++kc) {
    const int kb = kc * 32 + lg * 8;
    short8 a0 = *(const short8*)(hb + rowA0 + kb);
    short8 a1 = *(const short8*)(hb + rowA1 + kb);
#pragma unroll
    for (int nb = 0; nb < 8; ++nb) {
      short8 bfrag = *(const short8*)&Wl[nb * 16 + l15][kb];
      acc[0][nb] = __builtin_amdgcn_mfma_f32_16x16x32_bf16(a0, bfrag, acc[0][nb], 0, 0, 0);
      acc[1][nb] = __builtin_amdgcn_mfma_f32_16x16x32_bf16(a1, bfrag, acc[1][nb], 0, 0, 0);
    }
  }

  float av_s[8], av_d[8];
#pragma unroll
  for (int nb = 0; nb < 8; ++nb) {
    av_s[nb] = asrc[nb * 16 + l15];
    av_d[nb] = adst[nb * 16 + l15];
  }

#pragma unroll
  for (int rb = 0; rb < 2; ++rb) {
#pragma unroll
    for (int r = 0; r < 4; ++r) {
      int node = base + wv * 32 + rb * 16 + lg * 4 + r;
      bool ok = node < N_NODES;
      if (ok) {
#pragma unroll
        for (int nb = 0; nb < 4; ++nb) {
          unsigned int pk = bf16pair(acc[rb][nb][r], acc[rb][nb + 4][r]);
          xlp[(size_t)node * 64 + nb * 16 + l15] = pk;
        }
      }
      float p0 = acc[rb][0][r] * av_s[0] + acc[rb][1][r] * av_s[1];
      float p1 = acc[rb][2][r] * av_s[2] + acc[rb][3][r] * av_s[3];
      float p2 = acc[rb][4][r] * av_s[4] + acc[rb][5][r] * av_s[5];
      float p3 = acc[rb][6][r] * av_s[6] + acc[rb][7][r] * av_s[7];
      float q0 = acc[rb][0][r] * av_d[0] + acc[rb][1][r] * av_d[1];
      float q1 = acc[rb][2][r] * av_d[2] + acc[rb][3][r] * av_d[3];
      float q2 = acc[rb][4][r] * av_d[2 + 2] + acc[rb][5][r] * av_d[5];
      float q3 = acc[rb][6][r] * av_d[6] + acc[rb][7][r] * av_d[7];
#pragma unroll
      for (int o = 1; o <= 8; o <<= 1) {
        p0 += __shfl_xor(p0, o, 64);
        p1 += __shfl_xor(p1, o, 64);
        p2 += __shfl_xor(p2, o, 64);
        p3 += __shfl_xor(p3, o, 64);
        q0 += __shfl_xor(q0, o, 64);
        q1 += __shfl_xor(q1, o, 64);
        q2 += __shfl_xor(q2, o, 64);
        q3 += __shfl_xor(q3, o, 64);
      }
      if (ok && l15 == 0) {
        esrc[node * 4 + 0] = p0;
        esrc[node * 4 + 1] = p1;
        esrc[node * 4 + 2] = p2;
        esrc[node * 4 + 3] = p3;
        edst[node * 4 + 0] = q0;
        edst[node * 4 + 1] = q1;
        edst[node * 4 + 2] = q2;
        edst[node * 4 + 3] = q3;
      }
    }
  }
}

// single-pass softmax aggregation; per-edge weights precomputed (qw).
// Wave per node; 8-edge masked chunks, per-lane selected sums only.
__global__ __launch_bounds__(256) void gat_agg_kernel(const unsigned int* __restrict__ xlp,
                                                      const float* __restrict__ esrc,
                                                      const float* __restrict__ edst,
                                                      const float4* __restrict__ qw,
                                                      const int* __restrict__ off,
                                                      const int* __restrict__ eadj,
                                                      const float* __restrict__ gbias,
                                                      const float* __restrict__ lng,
                                                      const float* __restrict__ lnb,
                                                      float* __restrict__ h,
                                                      unsigned short* __restrict__ hb) {
  const int tid = threadIdx.x;
  const int lane = tid & 63;
  const int i = blockIdx.x * 4 + (tid >> 6);
  const int hd0 = lane >> 5;

  // self-loop contribution
  const float4 ed = *(const float4*)(edst + (size_t)i * 4);
  const float4 e0 = *(const float4*)(esrc + (size_t)i * 4);
  float w0 = __expf(lrelu(e0.x + ed.x));
  float w1 = __expf(lrelu(e0.y + ed.y));
  float w2 = __expf(lrelu(e0.z + ed.z));
  float w3 = __expf(lrelu(e0.w + ed.w));
  const unsigned int* xp = xlp + lane;
  const unsigned int vi = xp[(unsigned)i << 6];
  float qA0 = (hd0 == 0 ? w0 : w1);
  float qB0 = (hd0 == 0 ? w2 : w3);
  float sA = qA0, sB = qB0;
  float accA = __uint_as_float(vi << 16) * qA0;
  float accB = __uint_as_float(vi & 0xffff0000u) * qB0;

  const int beg = off[i], end = off[i + 1];
  for (int j0 = beg; j0 < end; j0 += 8) {
    int idxs[8];
#pragma unroll
    for (int t = 0; t < 8; ++t) {
      int jj = j0 + t;
      idxs[t] = eadj[jj < end ? jj : end - 1];
    }
    float4 Qs[8];
#pragma unroll
    for (int t = 0; t < 8; ++t) {
      int jj = j0 + t;
      Qs[t] = qw[jj < end ? jj : end - 1];
    }
    unsigned int vs[8];
#pragma unroll
    for (int t = 0; t < 8; ++t) vs[t] = xp[(unsigned)idxs[t] << 6];
#pragma unroll
    for (int t = 0; t < 8; ++t) {
      const bool valid = (j0 + t) < end;
      float qA = hd0 == 0 ? Qs[t].x : Qs[t].y;
      float qB = hd0 == 0 ? Qs[t].z : Qs[t].w;
      qA = valid ? qA : 0.f;
      qB = valid ? qB : 0.f;
      sA += qA;
      sB += qB;
      accA = fmaf(__uint_as_float(vs[t] << 16), qA, accA);
      accB = fmaf(__uint_as_float(vs[t] & 0xffff0000u), qB, accB);
    }
  }

  float o0 = accA / (sA + 1e-16f) + gbias[lane];
  float o1 = accB / (sB + 1e-16f) + gbias[lane + 64];
  float mu = wave_sum64(o0 + o1) * (1.f / 128.f);
  float d0 = o0 - mu, d1 = o1 - mu;
  float var = wave_sum64(d0 * d0 + d1 * d1) * (1.f / 128.f);
  float r = rsqrtf(var + LN_EPS);
  float hn0 = fmaxf(d0 * r * lng[lane] + lnb[lane], 0.f);
  float hn1 = fmaxf(d1 * r * lng[lane + 64] + lnb[lane + 64], 0.f);
  float nh0 = h[(size_t)i * HID + lane] + hn0;
  float nh1 = h[(size_t)i * HID + 64 + lane] + hn1;
  h[(size_t)i * HID + lane] = nh0;
  h[(size_t)i * HID + 64 + lane] = nh1;
  hb[(size_t)i * HID + lane] = bf16r(nh0);
  hb[(size_t)i * HID + 64 + lane] = bf16r(nh1);
}

__device__ __forceinline__ int lower_bound_dev(const int* a, int n, int v) {
  int lo = 0, hi = n;
  while (lo < hi) {
    int mid = (lo + hi) >> 1;
    if (a[mid] < v) lo = mid + 1; else hi = mid;
  }
  return lo;
}

// per-batch mean pool; grid (B, 4)
__global__ __launch_bounds__(256) void pool_kernel(const float* __restrict__ h,
                                                   const int* __restrict__ batch,
                                                   float* __restrict__ pooled) {
  __shared__ float red[256];
  int b = blockIdx.x, tid = threadIdx.x;
  int start = lower_bound_dev(batch, N_NODES, b);
  int end = lower_bound_dev(batch, N_NODES, b + 1);
  int cl = tid & 31, g = tid >> 5;
  int c = cl + blockIdx.y * 32;
  float acc = 0.f;
  for (int n = start + g; n < end; n += 8) acc += h[(size_t)n * HID + c];
  red[tid] = acc;
  __syncthreads();
  if (g == 0) {
    float tot = 0.f;
#pragma unroll
    for (int k = 0; k < 8; ++k) tot += red[cl + 32 * k];
    float cntf = fmaxf((float)(end - start), 1.f);
    pooled[b * HID + c] = tot / cntf;
  }
}

// One wave per output element (m,c); lane-split K; two independent fused stages.
__global__ __launch_bounds__(256) void gemv2_kernel(
    const float* __restrict__ A1, int lda1, const float* __restrict__ W1,
    const float* __restrict__ b1, float* __restrict__ O1, int ldo1,
    int sh1, int K1, int relu1,
    const float* __restrict__ A2, int lda2, const float* __restrict__ W2,
    const float* __restrict__ b2, float* __restrict__ O2, int ldo2,
    int sh2, int K2, int relu2, int nw1, int nwTot) {
  int gw = (blockIdx.x * 256 + threadIdx.x) >> 6;
  int lane = threadIdx.x & 63;
  if (gw >= nwTot) return;
  const float *A, *W, *b;
  float* O;
  int lda, ldo, K, relu, m, c;
  if (gw < nw1) {
    A = A1; W = W1; b = b1; O = O1; lda = lda1; ldo = ldo1; K = K1; relu = relu1;
    m = gw >> sh1; c = gw & ((1 << sh1) - 1);
  } else {
    int g2 = gw - nw1;
    A = A2; W = W2; b = b2; O = O2; lda = lda2; ldo = ldo2; K = K2; relu = relu2;
    m = g2 >> sh2; c = g2 & ((1 << sh2) - 1);
  }
  const float* a = A + (size_t)m * lda;
  const float* w = W + (size_t)c * K;
  float acc = 0.f;
  for (int k = lane * 2; k < K; k += 128) {
    float2 av = *(const float2*)(a + k);
    float2 wv = *(const float2*)(w + k);
    acc += av.x * wv.x + av.y * wv.y;
  }
  acc = wave_sum64(acc);
  if (lane == 0) {
    acc += b[c];
    if (relu) acc = fmaxf(acc, 0.f);
    O[(size_t)m * ldo + c] = acc;
  }
}

// z1 = relu([att1|att2|seqh|strh] @ p1_W.T + p1_b); wave per (m,c)
__global__ __launch_bounds__(256) void z1_kernel(const float* __restrict__ att1,
                                                 const float* __restrict__ att2,
                                                 const float* __restrict__ seqh,
                                                 const float* __restrict__ strh,
                                                 const float* __restrict__ p1_W,
                                                 const float* __restrict__ p1_b,
                                                 float* __restrict__ z1) {
  int gw = (blockIdx.x * 256 + threadIdx.x) >> 6;
  int lane = threadIdx.x & 63;
  int m = gw >> 8, c = gw & 255;
  const float* segs[4] = {att1 + m * HD, att2 + m * HD, seqh + m * HD, strh + m * HD};
  const float* w = p1_W + (size_t)c * (4 * HD);
  float acc = 0.f;
#pragma unroll
  for (int s = 0; s < 4; ++s) {
    const float* a = segs[s];
#pragma unroll
    for (int k = lane * 2; k < HD; k += 128) {
      float2 av = *(const float2*)(a + k);
      float2 wv = *(const float2*)(w + s * HD + k);
      acc += av.x * wv.x + av.y * wv.y;
    }
  }
  acc = wave_sum64(acc);
  if (lane == 0) z1[m * HD + c] = fmaxf(acc + p1_b[c], 0.f);
}

extern "C" void kernel_launch(void* const* d_in, const int* in_sizes, int n_in,
                              void* d_out, int out_size, void* d_ws, size_t ws_size,
                              hipStream_t stream) {
  const float* seq_emb = (const float*)d_in[0];
  const float* x       = (const float*)d_in[1];
  const int* eidx      = (const int*)d_in[2];
  const int* batch     = (const int*)d_in[3];
  const float* ne_W = (const float*)d_in[4];
  const float* ne_b = (const float*)d_in[5];
  const float* gat_W = (const float*)d_in[6];
  const float* gat_asrc = (const float*)d_in[7];
  const float* gat_adst = (const float*)d_in[8];
  const float* gat_b = (const float*)d_in[9];
  const float* ln_g = (const float*)d_in[10];
  const float* ln_b = (const float*)d_in[11];
  const float* op1_W = (const float*)d_in[12];
  const float* op1_b = (const float*)d_in[13];
  const float* op2_W = (const float*)d_in[14];
  const float* op2_b = (const float*)d_in[15];
  const float* sp_W = (const float*)d_in[16];
  const float* sp_b = (const float*)d_in[17];
  const float* stp_W = (const float*)d_in[18];
  const float* stp_b = (const float*)d_in[19];
  const float* a1_Wi = (const float*)d_in[20];
  const float* a1_bi = (const float*)d_in[21];
  const float* a1_Wo = (const float*)d_in[22];
  const float* a1_bo = (const float*)d_in[23];
  const float* a2_Wi = (const float*)d_in[24];
  const float* a2_bi = (const float*)d_in[25];
  const float* a2_Wo = (const float*)d_in[26];
  const float* a2_bo = (const float*)d_in[27];
  const float* p1_W = (const float*)d_in[28];
  const float* p1_b = (const float*)d_in[29];
  const float* p2_W = (const float*)d_in[30];
  const float* p2_b = (const float*)d_in[31];
  const float* p3_W = (const float*)d_in[32];
  const float* p3_b = (const float*)d_in[33];

  const int E = in_sizes[2] / 2;
  const int* e_src = eidx;
  const int* e_dst = eidx + E;

  char* p = (char*)d_ws;
  auto alloc = [&](size_t bytes) -> void* {
    void* r = p;
    p += (bytes + 255) & ~(size_t)255;
    return r;
  };
  float* h    = (float*)alloc(sizeof(float) * (size_t)N_NODES * HID);
  unsigned short* hbuf = (unsigned short*)alloc(sizeof(unsigned short) * (size_t)N_NODES * HID);
  unsigned short* wb   = (unsigned short*)alloc(sizeof(unsigned short) * L_LAYERS * HID * HID);
  unsigned int* xlp = (unsigned int*)alloc(sizeof(unsigned int) * (size_t)N_NODES * 64);
  float* esrc = (float*)alloc(sizeof(float) * (size_t)N_NODES * 4);
  float* edst = (float*)alloc(sizeof(float) * (size_t)N_NODES * 4);
  int* cnt    = (int*)alloc(sizeof(int) * N_NODES);
  int* cur    = (int*)alloc(sizeof(int) * N_NODES);
  int* off    = (int*)alloc(sizeof(int) * (N_NODES + 1));
  int* eadj   = (int*)alloc(sizeof(int) * (size_t)E);
  float4* qw  = (float4*)alloc(sizeof(float4) * (size_t)E);
  int* bsum   = (int*)alloc(sizeof(int) * 128);
  float* pooled = (float*)alloc(sizeof(float) * B_GRAPHS * HID);
  float* t1B   = (float*)alloc(sizeof(float) * B_GRAPHS * HID);
  float* sembB = (float*)alloc(sizeof(float) * B_GRAPHS * HID);
  float* seqhB = (float*)alloc(sizeof(float) * B_GRAPHS * HD);
  float* strhB = (float*)alloc(sizeof(float) * B_GRAPHS * HD);
  float* v1B   = (float*)alloc(sizeof(float) * B_GRAPHS * HD);
  float* v2B   = (float*)alloc(sizeof(float) * B_GRAPHS * HD);
  float* att1B = (float*)alloc(sizeof(float) * B_GRAPHS * HD);
  float* att2B = (float*)alloc(sizeof(float) * B_GRAPHS * HD);
  float* z1B   = (float*)alloc(sizeof(float) * B_GRAPHS * HD);
  float* z2B   = (float*)alloc(sizeof(float) * B_GRAPHS * (HD / 2));

  hipMemsetAsync(cnt, 0, sizeof(int) * N_NODES, stream);
  hipMemsetAsync(cur, 0, sizeof(int) * N_NODES, stream);

  const int SCAN_BLKS = (N_NODES + 1023) / 1024;  // 98
  ne_kernel<<<N_NODES * HID / 256, 256, 0, stream>>>(x, ne_W, ne_b, h, hbuf);
  wcvt_kernel<<<(L_LAYERS * HID * HID + 255) / 256, 256, 0, stream>>>(gat_W, wb);
  hist_kernel<<<(E + 255) / 256, 256, 0, stream>>>(e_dst, cnt, E);
  scan1_kernel<<<SCAN_BLKS, 1024, 0, stream>>>(cnt, off, bsum, N_NODES);
  scan2_kernel<<<1, 64, 0, stream>>>(bsum, SCAN_BLKS);
  scan3_kernel<<<(N_NODES + 256) / 256, 256, 0, stream>>>(bsum, off, N_NODES, E);
  scatter_kernel<<<(E + 255) / 256, 256, 0, stream>>>(e_src, e_dst, off, cur, eadj, E);

  const unsigned EDGE_BLKS = (E + 255) / 256;
  for (int l = 0; l < L_LAYERS; ++l) {
    gat_xl_kernel<<<(N_NODES + 127) / 128, 256, 0, stream>>>(
        hbuf, wb + (size_t)l * HID * HID, gat_asrc + l * HID, gat_adst + l * HID,
        xlp, esrc, edst);
    edgew_kernel<<<EDGE_BLKS, 256, 0, stream>>>(eadj, off, esrc, edst, qw, E);
    gat_agg_kernel<<<N_NODES / 4, 256, 0, stream>>>(
        xlp, esrc, edst, qw, off, eadj, gat_b + l * HID, ln_g + l * HID, ln_b + l * HID,
        h, hbuf);
  }
  pool_kernel<<<dim3(B_GRAPHS, 4), 256, 0, stream>>>(h, batch, pooled);

  // ---- head: 8 dependency levels, wave-per-output ----
  const float* a1_Wv = a1_Wi + 2 * HD * HD;
  const float* a1_bv = a1_bi + 2 * HD;
  const float* a2_Wv = a2_Wi + 2 * HD * HD;
  const float* a2_bv = a2_bi + 2 * HD;
  auto nblk = [](int waves) { return (unsigned)((waves + 3) / 4); };

  {
    int nw1 = B_GRAPHS * HD, nwT = nw1 + B_GRAPHS * HID;
    gemv2_kernel<<<nblk(nwT), 256, 0, stream>>>(
        seq_emb, SEQ_LEN, sp_W, sp_b, seqhB, HD, 8, SEQ_LEN, 0,
        pooled, HID, op1_W, op1_b, t1B, HID, 7, HID, 1, nw1, nwT);
  }
  {
    int nw1 = B_GRAPHS * HD, nwT = nw1 + B_GRAPHS * HID;
    gemv2_kernel<<<nblk(nwT), 256, 0, stream>>>(
        seqhB, HD, a2_Wv, a2_bv, v2B, HD, 8, HD, 0,
        t1B, HID, op2_W, op2_b, sembB, HID, 7, HID, 0, nw1, nwT);
  }
  {
    int nw1 = B_GRAPHS * HD, nwT = nw1 + B_GRAPHS * HD;
    gemv2_kernel<<<nblk(nwT), 256, 0, stream>>>(
        v2B, HD, a2_Wo, a2_bo, att2B, HD, 8, HD, 0,
        sembB, HID, stp_W, stp_b, strhB, HD, 8, HID, 0, nw1, nwT);
  }
  {
    int nwT = B_GRAPHS * HD;
    gemv2_kernel<<<nblk(nwT), 256, 0, stream>>>(
        strhB, HD, a1_Wv, a1_bv, v1B, HD, 8, HD, 0,
        nullptr, 0, nullptr, nullptr, nullptr, 0, 0, 0, 0, nwT, nwT);
  }
  {
    int nwT = B_GRAPHS * HD;
    gemv2_kernel<<<nblk(nwT), 256, 0, stream>>>(
        v1B, HD, a1_Wo, a1_bo, att1B, HD, 8, HD, 0,
        nullptr, 0, nullptr, nullptr, nullptr, 0, 0, 0, 0, nwT, nwT);
  }
  z1_kernel<<<nblk(B_GRAPHS * HD), 256, 0, stream>>>(att1B, att2B, seqhB, strhB, p1_W, p1_b, z1B);
  {
    int nwT = B_GRAPHS * (HD / 2);
    gemv2_kernel<<<nblk(nwT), 256, 0, stream>>>(
        z1B, HD, p2_W, p2_b, z2B, HD / 2, 7, HD, 1,
        nullptr, 0, nullptr, nullptr, nullptr, 0, 0, 0, 0, nwT, nwT);
  }
  {
    int nwT = B_GRAPHS;
    gemv2_kernel<<<nblk(nwT), 256, 0, stream>>>(
        z2B, HD / 2, p3_W, p3_b, (float*)d_out, 1, 0, HD / 2, 0,
        nullptr, 0, nullptr, nullptr, nullptr, 0, 0, 0, 0, nwT, nwT);
  }
}

// Round 8
// 644.073 us; speedup vs baseline: 1.0871x; 1.0871x over previous
//
#include <hip/hip_runtime.h>
#include <hip/hip_bf16.h>

#define N_NODES 100000
#define NFEAT 9
#define HID 128
#define B_GRAPHS 64
#define SEQ_LEN 768
#define HD 256
#define L_LAYERS 4
#define LN_EPS 1e-5f

typedef __attribute__((ext_vector_type(8))) short short8;
typedef __attribute__((ext_vector_type(4))) float f32x4;

__device__ __forceinline__ float lrelu(float v) { return v > 0.f ? v : 0.2f * v; }

__device__ __forceinline__ float wave_sum64(float x) {
#pragma unroll
  for (int o = 32; o >= 1; o >>= 1) x += __shfl_xor(x, o, 64);
  return x;
}

__device__ __forceinline__ unsigned short bf16r(float v) {
  unsigned int u = __float_as_uint(v);
  return (unsigned short)((u + 0x7fffu + ((u >> 16) & 1u)) >> 16);
}
// pack: low16 = bf16(lo), high16 = bf16(hi)
__device__ __forceinline__ unsigned int bf16pair(float lo, float hi) {
  unsigned int ul = __float_as_uint(lo);
  unsigned int uh = __float_as_uint(hi);
  ul = (ul + 0x7fffu + ((ul >> 16) & 1u)) >> 16;
  uh = (uh + 0x7fffu + ((uh >> 16) & 1u)) & 0xffff0000u;
  return ul | uh;
}

// h = relu(x @ ne_W.T + ne_b); also emits bf16 copy
__global__ __launch_bounds__(256) void ne_kernel(const float* __restrict__ x,
                                                 const float* __restrict__ W,
                                                 const float* __restrict__ b,
                                                 float* __restrict__ h,
                                                 unsigned short* __restrict__ hb) {
  int idx = blockIdx.x * 256 + threadIdx.x;
  int n = idx >> 7, c = idx & 127;
  const float* xr = x + n * NFEAT;
  const float* wr = W + c * NFEAT;
  float acc = b[c];
#pragma unroll
  for (int k = 0; k < NFEAT; ++k) acc += xr[k] * wr[k];
  acc = fmaxf(acc, 0.f);
  h[idx] = acc;
  hb[idx] = bf16r(acc);
}

// convert all L layers of gat_W to bf16
__global__ __launch_bounds__(256) void wcvt_kernel(const float* __restrict__ W,
                                                   unsigned short* __restrict__ wb) {
  int idx = blockIdx.x * 256 + threadIdx.x;
  if (idx < L_LAYERS * HID * HID) wb[idx] = bf16r(W[idx]);
}

// was8[l][j][k]: j<4: sum_c W[l][j*32+c][k]*asrc[l][j*32+c]; j in 4..7: adst; j>=8: 0
__global__ __launch_bounds__(256) void wprep_kernel(const float* __restrict__ W,
                                                    const float* __restrict__ asrc,
                                                    const float* __restrict__ adst,
                                                    unsigned short* __restrict__ was8) {
  int t = blockIdx.x * 256 + threadIdx.x;  // L*16*128
  if (t >= L_LAYERS * 16 * 128) return;
  int l = t >> 11;
  int rem = t & 2047;
  int j = rem >> 7;
  int k = rem & 127;
  float sum = 0.f;
  if (j < 8) {
    int head = j & 3;
    const float* a = (j < 4) ? (asrc + l * HID + head * 32) : (adst + l * HID + head * 32);
    const float* Wl = W + (size_t)l * HID * HID + (size_t)(head * 32) * HID + k;
#pragma unroll 8
    for (int c = 0; c < 32; ++c) sum += Wl[(size_t)c * HID] * a[c];
  }
  was8[t] = bf16r(sum);
}

__global__ __launch_bounds__(256) void hist_kernel(const int* __restrict__ dst,
                                                   int* __restrict__ cnt, int E) {
  int i = blockIdx.x * 256 + threadIdx.x;
  if (i < E) atomicAdd(&cnt[dst[i]], 1);
}

// hierarchical exclusive scan
__global__ __launch_bounds__(1024) void scan1_kernel(const int* __restrict__ cnt,
                                                     int* __restrict__ off,
                                                     int* __restrict__ bsum, int n) {
  __shared__ int ws[16];
  __shared__ int wx[16];
  int tid = threadIdx.x, lane = tid & 63, w = tid >> 6;
  int i = blockIdx.x * 1024 + tid;
  int v = (i < n) ? cnt[i] : 0;
  int x = v;
#pragma unroll
  for (int o = 1; o < 64; o <<= 1) {
    int t = __shfl_up(x, o, 64);
    if (lane >= o) x += t;
  }
  if (lane == 63) ws[w] = x;
  __syncthreads();
  if (tid == 0) {
    int r = 0;
#pragma unroll
    for (int j = 0; j < 16; ++j) { int t = ws[j]; wx[j] = r; r += t; }
    bsum[blockIdx.x] = r;
  }
  __syncthreads();
  if (i < n) off[i] = wx[w] + x - v;
}

__global__ void scan2_kernel(int* __restrict__ bsum, int nb) {
  int lane = threadIdx.x;
  int i0 = lane * 2, i1 = i0 + 1;
  int a = (i0 < nb) ? bsum[i0] : 0;
  int b = (i1 < nb) ? bsum[i1] : 0;
  int s = a + b, x = s;
#pragma unroll
  for (int o = 1; o < 64; o <<= 1) {
    int t = __shfl_up(x, o, 64);
    if (lane >= o) x += t;
  }
  int excl = x - s;
  if (i0 < nb) bsum[i0] = excl;
  if (i1 < nb) bsum[i1] = excl + a;
}

__global__ __launch_bounds__(256) void scan3_kernel(const int* __restrict__ bsum,
                                                    int* __restrict__ off, int n, int total) {
  int i = blockIdx.x * 256 + threadIdx.x;
  if (i < n) off[i] += bsum[i >> 10];
  else if (i == n) off[i] = total;
}

__global__ __launch_bounds__(256) void scatter_kernel(const int* __restrict__ src,
                                                      const int* __restrict__ dst,
                                                      const int* __restrict__ off,
                                                      int* __restrict__ cur,
                                                      int* __restrict__ eadj, int E) {
  int i = blockIdx.x * 256 + threadIdx.x;
  if (i < E) {
    int d = dst[i];
    int pos = atomicAdd(&cur[d], 1);
    eadj[off[d] + pos] = src[i];
  }
}

// per-edge softmax weights; dst recovered by binary search in off
__global__ __launch_bounds__(256) void edgew_kernel(const int* __restrict__ eadj,
                                                    const int* __restrict__ off,
                                                    const float* __restrict__ esrc,
                                                    const float* __restrict__ edst,
                                                    float4* __restrict__ qw, int E) {
  int j = blockIdx.x * 256 + threadIdx.x;
  if (j >= E) return;
  int s = eadj[j];
  int lo = 0, hi = N_NODES;  // invariant: off[lo] <= j < off[hi]
  while (lo + 1 < hi) {
    int mid = (lo + hi) >> 1;
    if (off[mid] <= j) lo = mid; else hi = mid;
  }
  const float4 es = *(const float4*)(esrc + (size_t)s * 4);
  const float4 ed = *(const float4*)(edst + (size_t)lo * 4);
  float4 q;
  q.x = __expf(lrelu(es.x + ed.x));
  q.y = __expf(lrelu(es.y + ed.y));
  q.z = __expf(lrelu(es.z + ed.z));
  q.w = __expf(lrelu(es.w + ed.w));
  qw[j] = q;
}

// xl = h @ W.T via bf16 MFMA. 128 rows/block, 4 waves (32 rows each), full 128 cols.
// Logits computed with one extra MFMA B-operand (was8), no shuffles.
__global__ __launch_bounds__(256) void gat_xl_kernel(const unsigned short* __restrict__ hb,
                                                     const unsigned short* __restrict__ wb,
                                                     const unsigned short* __restrict__ wasb,
                                                     unsigned int* __restrict__ xlp,
                                                     float* __restrict__ esrc,
                                                     float* __restrict__ edst) {
  __shared__ unsigned short Wl[128][136];  // +8 pad: 2-way bank alias only
  const int tid = threadIdx.x;
  const int lane = tid & 63;
  const int wv = tid >> 6;
  const int base = blockIdx.x * 128;
  const int l15 = lane & 15;
  const int lg = lane >> 4;  // 0..3

  // stage W (bf16) into LDS
#pragma unroll
  for (int t = 0; t < 8; ++t) {
    int f8 = tid + t * 256;          // 2048 chunks of 8 ushorts
    int row = f8 >> 4, c8 = (f8 & 15) * 8;
    uint4 v = *(const uint4*)(wb + row * HID + c8);
    *(uint4*)&Wl[row][c8] = v;
  }
  __syncthreads();

  f32x4 acc[2][8];
  f32x4 acc_e[2];
#pragma unroll
  for (int rb = 0; rb < 2; ++rb) {
#pragma unroll
    for (int nb = 0; nb < 8; ++nb) acc[rb][nb] = (f32x4){0.f, 0.f, 0.f, 0.f};
    acc_e[rb] = (f32x4){0.f, 0.f, 0.f, 0.f};
  }

  int n0 = base + wv * 32 + l15;
  int n1 = n0 + 16;
  if (n0 >= N_NODES) n0 = N_NODES - 1;
  if (n1 >= N_NODES) n1 = N_NODES - 1;
  const size_t rowA0 = (size_t)n0 * HID;
  const size_t rowA1 = (size_t)n1 * HID;

#pragma unroll
  for (int kc = 0; kc < 4; ++kc) {
    const int kb = kc * 32 + lg * 8;
    short8 a0 = *(const short8*)(hb + rowA0 + kb);
    short8 a1 = *(const short8*)(hb + rowA1 + kb);
    short8 efrag = *(const short8*)(wasb + l15 * HID + kb);
    acc_e[0] = __builtin_amdgcn_mfma_f32_16x16x32_bf16(a0, efrag, acc_e[0], 0, 0, 0);
    acc_e[1] = __builtin_amdgcn_mfma_f32_16x16x32_bf16(a1, efrag, acc_e[1], 0, 0, 0);
#pragma unroll
    for (int nb = 0; nb < 8; ++nb) {
      short8 bfrag = *(const short8*)&Wl[nb * 16 + l15][kb];
      acc[0][nb] = __builtin_amdgcn_mfma_f32_16x16x32_bf16(a0, bfrag, acc[0][nb], 0, 0, 0);
      acc[1][nb] = __builtin_amdgcn_mfma_f32_16x16x32_bf16(a1, bfrag, acc[1][nb], 0, 0, 0);
    }
  }

#pragma unroll
  for (int rb = 0; rb < 2; ++rb) {
#pragma unroll
    for (int r = 0; r < 4; ++r) {
      int node = base + wv * 32 + rb * 16 + lg * 4 + r;
      if (node < N_NODES) {
#pragma unroll
        for (int nb = 0; nb < 4; ++nb) {
          unsigned int pk = bf16pair(acc[rb][nb][r], acc[rb][nb + 4][r]);
          xlp[(size_t)node * 64 + nb * 16 + l15] = pk;
        }
        float ev = acc_e[rb][r];
        if (l15 < 4) esrc[node * 4 + l15] = ev;
        else if (l15 < 8) edst[node * 4 + (l15 - 4)] = ev;
      }
    }
  }
}

// single-pass softmax aggregation; per-edge weights precomputed (qw).
// Wave per node; 4-edge software pipeline (round-6 version, 24 VGPR).
__global__ __launch_bounds__(256) void gat_agg_kernel(const unsigned int* __restrict__ xlp,
                                                      const float* __restrict__ esrc,
                                                      const float* __restrict__ edst,
                                                      const float4* __restrict__ qw,
                                                      const int* __restrict__ off,
                                                      const int* __restrict__ eadj,
                                                      const float* __restrict__ gbias,
                                                      const float* __restrict__ lng,
                                                      const float* __restrict__ lnb,
                                                      float* __restrict__ h,
                                                      unsigned short* __restrict__ hb) {
  const int tid = threadIdx.x;
  const int lane = tid & 63;
  const int i = blockIdx.x * 4 + (tid >> 6);
  const int hd0 = lane >> 5;

  const float4 ed = *(const float4*)(edst + (size_t)i * 4);
  const float4 e0 = *(const float4*)(esrc + (size_t)i * 4);
  float w0 = __expf(lrelu(e0.x + ed.x));
  float w1 = __expf(lrelu(e0.y + ed.y));
  float w2 = __expf(lrelu(e0.z + ed.z));
  float w3 = __expf(lrelu(e0.w + ed.w));
  float s0 = w0, s1 = w1, s2 = w2, s3 = w3;
  const unsigned int* xp = xlp + lane;
  const unsigned int vi = xp[(size_t)i * 64];
  float accA = __uint_as_float(vi << 16) * (hd0 == 0 ? w0 : w1);
  float accB = __uint_as_float(vi & 0xffff0000u) * (hd0 == 0 ? w2 : w3);
  const int beg = off[i], end = off[i + 1];
  int j = beg;
  for (; j + 4 <= end; j += 4) {
    const int sa = eadj[j + 0];
    const int sb = eadj[j + 1];
    const int sc = eadj[j + 2];
    const int sd = eadj[j + 3];
    const float4 Qa = qw[j + 0];
    const float4 Qb = qw[j + 1];
    const float4 Qc = qw[j + 2];
    const float4 Qd = qw[j + 3];
    const unsigned int va = xp[(size_t)sa * 64];
    const unsigned int vb = xp[(size_t)sb * 64];
    const unsigned int vc = xp[(size_t)sc * 64];
    const unsigned int vd = xp[(size_t)sd * 64];
    s0 += Qa.x + Qb.x + Qc.x + Qd.x;
    s1 += Qa.y + Qb.y + Qc.y + Qd.y;
    s2 += Qa.z + Qb.z + Qc.z + Qd.z;
    s3 += Qa.w + Qb.w + Qc.w + Qd.w;
    accA += __uint_as_float(va << 16) * (hd0 == 0 ? Qa.x : Qa.y) +
            __uint_as_float(vb << 16) * (hd0 == 0 ? Qb.x : Qb.y) +
            __uint_as_float(vc << 16) * (hd0 == 0 ? Qc.x : Qc.y) +
            __uint_as_float(vd << 16) * (hd0 == 0 ? Qd.x : Qd.y);
    accB += __uint_as_float(va & 0xffff0000u) * (hd0 == 0 ? Qa.z : Qa.w) +
            __uint_as_float(vb & 0xffff0000u) * (hd0 == 0 ? Qb.z : Qb.w) +
            __uint_as_float(vc & 0xffff0000u) * (hd0 == 0 ? Qc.z : Qc.w) +
            __uint_as_float(vd & 0xffff0000u) * (hd0 == 0 ? Qd.z : Qd.w);
  }
  for (; j < end; ++j) {
    const int sc = eadj[j];
    const float4 Q = qw[j];
    const unsigned int v = xp[(size_t)sc * 64];
    s0 += Q.x; s1 += Q.y; s2 += Q.z; s3 += Q.w;
    accA += __uint_as_float(v << 16) * (hd0 == 0 ? Q.x : Q.y);
    accB += __uint_as_float(v & 0xffff0000u) * (hd0 == 0 ? Q.z : Q.w);
  }
  float dA = (hd0 == 0 ? s0 : s1) + 1e-16f;
  float dB = (hd0 == 0 ? s2 : s3) + 1e-16f;
  float o0 = accA / dA + gbias[lane];
  float o1 = accB / dB + gbias[lane + 64];
  float mu = wave_sum64(o0 + o1) * (1.f / 128.f);
  float d0 = o0 - mu, d1 = o1 - mu;
  float var = wave_sum64(d0 * d0 + d1 * d1) * (1.f / 128.f);
  float r = rsqrtf(var + LN_EPS);
  float hn0 = fmaxf(d0 * r * lng[lane] + lnb[lane], 0.f);
  float hn1 = fmaxf(d1 * r * lng[lane + 64] + lnb[lane + 64], 0.f);
  float nh0 = h[(size_t)i * HID + lane] + hn0;
  float nh1 = h[(size_t)i * HID + 64 + lane] + hn1;
  h[(size_t)i * HID + lane] = nh0;
  h[(size_t)i * HID + 64 + lane] = nh1;
  hb[(size_t)i * HID + lane] = bf16r(nh0);
  hb[(size_t)i * HID + 64 + lane] = bf16r(nh1);
}

__device__ __forceinline__ int lower_bound_dev(const int* a, int n, int v) {
  int lo = 0, hi = n;
  while (lo < hi) {
    int mid = (lo + hi) >> 1;
    if (a[mid] < v) lo = mid + 1; else hi = mid;
  }
  return lo;
}

// per-batch mean pool; grid (B, 4)
__global__ __launch_bounds__(256) void pool_kernel(const float* __restrict__ h,
                                                   const int* __restrict__ batch,
                                                   float* __restrict__ pooled) {
  __shared__ float red[256];
  int b = blockIdx.x, tid = threadIdx.x;
  int start = lower_bound_dev(batch, N_NODES, b);
  int end = lower_bound_dev(batch, N_NODES, b + 1);
  int cl = tid & 31, g = tid >> 5;
  int c = cl + blockIdx.y * 32;
  float acc = 0.f;
  for (int n = start + g; n < end; n += 8) acc += h[(size_t)n * HID + c];
  red[tid] = acc;
  __syncthreads();
  if (g == 0) {
    float tot = 0.f;
#pragma unroll
    for (int k = 0; k < 8; ++k) tot += red[cl + 32 * k];
    float cntf = fmaxf((float)(end - start), 1.f);
    pooled[b * HID + c] = tot / cntf;
  }
}

// One wave per output element (m,c); lane-split K; two independent fused stages.
__global__ __launch_bounds__(256) void gemv2_kernel(
    const float* __restrict__ A1, int lda1, const float* __restrict__ W1,
    const float* __restrict__ b1, float* __restrict__ O1, int ldo1,
    int sh1, int K1, int relu1,
    const float* __restrict__ A2, int lda2, const float* __restrict__ W2,
    const float* __restrict__ b2, float* __restrict__ O2, int ldo2,
    int sh2, int K2, int relu2, int nw1, int nwTot) {
  int gw = (blockIdx.x * 256 + threadIdx.x) >> 6;
  int lane = threadIdx.x & 63;
  if (gw >= nwTot) return;
  const float *A, *W, *b;
  float* O;
  int lda, ldo, K, relu, m, c;
  if (gw < nw1) {
    A = A1; W = W1; b = b1; O = O1; lda = lda1; ldo = ldo1; K = K1; relu = relu1;
    m = gw >> sh1; c = gw & ((1 << sh1) - 1);
  } else {
    int g2 = gw - nw1;
    A = A2; W = W2; b = b2; O = O2; lda = lda2; ldo = ldo2; K = K2; relu = relu2;
    m = g2 >> sh2; c = g2 & ((1 << sh2) - 1);
  }
  const float* a = A + (size_t)m * lda;
  const float* w = W + (size_t)c * K;
  float acc = 0.f;
  for (int k = lane * 2; k < K; k += 128) {
    float2 av = *(const float2*)(a + k);
    float2 wv = *(const float2*)(w + k);
    acc += av.x * wv.x + av.y * wv.y;
  }
  acc = wave_sum64(acc);
  if (lane == 0) {
    acc += b[c];
    if (relu) acc = fmaxf(acc, 0.f);
    O[(size_t)m * ldo + c] = acc;
  }
}

// z1 = relu([att1|att2|seqh|strh] @ p1_W.T + p1_b); wave per (m,c)
__global__ __launch_bounds__(256) void z1_kernel(const float* __restrict__ att1,
                                                 const float* __restrict__ att2,
                                                 const float* __restrict__ seqh,
                                                 const float* __restrict__ strh,
                                                 const float* __restrict__ p1_W,
                                                 const float* __restrict__ p1_b,
                                                 float* __restrict__ z1) {
  int gw = (blockIdx.x * 256 + threadIdx.x) >> 6;
  int lane = threadIdx.x & 63;
  int m = gw >> 8, c = gw & 255;
  const float* segs[4] = {att1 + m * HD, att2 + m * HD, seqh + m * HD, strh + m * HD};
  const float* w = p1_W + (size_t)c * (4 * HD);
  float acc = 0.f;
#pragma unroll
  for (int s = 0; s < 4; ++s) {
    const float* a = segs[s];
#pragma unroll
    for (int k = lane * 2; k < HD; k += 128) {
      float2 av = *(const float2*)(a + k);
      float2 wv = *(const float2*)(w + s * HD + k);
      acc += av.x * wv.x + av.y * wv.y;
    }
  }
  acc = wave_sum64(acc);
  if (lane == 0) z1[m * HD + c] = fmaxf(acc + p1_b[c], 0.f);
}

extern "C" void kernel_launch(void* const* d_in, const int* in_sizes, int n_in,
                              void* d_out, int out_size, void* d_ws, size_t ws_size,
                              hipStream_t stream) {
  const float* seq_emb = (const float*)d_in[0];
  const float* x       = (const float*)d_in[1];
  const int* eidx      = (const int*)d_in[2];
  const int* batch     = (const int*)d_in[3];
  const float* ne_W = (const float*)d_in[4];
  const float* ne_b = (const float*)d_in[5];
  const float* gat_W = (const float*)d_in[6];
  const float* gat_asrc = (const float*)d_in[7];
  const float* gat_adst = (const float*)d_in[8];
  const float* gat_b = (const float*)d_in[9];
  const float* ln_g = (const float*)d_in[10];
  const float* ln_b = (const float*)d_in[11];
  const float* op1_W = (const float*)d_in[12];
  const float* op1_b = (const float*)d_in[13];
  const float* op2_W = (const float*)d_in[14];
  const float* op2_b = (const float*)d_in[15];
  const float* sp_W = (const float*)d_in[16];
  const float* sp_b = (const float*)d_in[17];
  const float* stp_W = (const float*)d_in[18];
  const float* stp_b = (const float*)d_in[19];
  const float* a1_Wi = (const float*)d_in[20];
  const float* a1_bi = (const float*)d_in[21];
  const float* a1_Wo = (const float*)d_in[22];
  const float* a1_bo = (const float*)d_in[23];
  const float* a2_Wi = (const float*)d_in[24];
  const float* a2_bi = (const float*)d_in[25];
  const float* a2_Wo = (const float*)d_in[26];
  const float* a2_bo = (const float*)d_in[27];
  const float* p1_W = (const float*)d_in[28];
  const float* p1_b = (const float*)d_in[29];
  const float* p2_W = (const float*)d_in[30];
  const float* p2_b = (const float*)d_in[31];
  const float* p3_W = (const float*)d_in[32];
  const float* p3_b = (const float*)d_in[33];

  const int E = in_sizes[2] / 2;
  const int* e_src = eidx;
  const int* e_dst = eidx + E;

  char* p = (char*)d_ws;
  auto alloc = [&](size_t bytes) -> void* {
    void* r = p;
    p += (bytes + 255) & ~(size_t)255;
    return r;
  };
  float* h    = (float*)alloc(sizeof(float) * (size_t)N_NODES * HID);
  unsigned short* hbuf = (unsigned short*)alloc(sizeof(unsigned short) * (size_t)N_NODES * HID);
  unsigned short* wb   = (unsigned short*)alloc(sizeof(unsigned short) * L_LAYERS * HID * HID);
  unsigned short* was8 = (unsigned short*)alloc(sizeof(unsigned short) * L_LAYERS * 16 * HID);
  unsigned int* xlp = (unsigned int*)alloc(sizeof(unsigned int) * (size_t)N_NODES * 64);
  float* esrc = (float*)alloc(sizeof(float) * (size_t)N_NODES * 4);
  float* edst = (float*)alloc(sizeof(float) * (size_t)N_NODES * 4);
  int* cnt    = (int*)alloc(sizeof(int) * N_NODES);
  int* cur    = (int*)alloc(sizeof(int) * N_NODES);
  int* off    = (int*)alloc(sizeof(int) * (N_NODES + 1));
  int* eadj   = (int*)alloc(sizeof(int) * (size_t)E);
  float4* qw  = (float4*)alloc(sizeof(float4) * (size_t)E);
  int* bsum   = (int*)alloc(sizeof(int) * 128);
  float* pooled = (float*)alloc(sizeof(float) * B_GRAPHS * HID);
  float* t1B   = (float*)alloc(sizeof(float) * B_GRAPHS * HID);
  float* sembB = (float*)alloc(sizeof(float) * B_GRAPHS * HID);
  float* seqhB = (float*)alloc(sizeof(float) * B_GRAPHS * HD);
  float* strhB = (float*)alloc(sizeof(float) * B_GRAPHS * HD);
  float* v1B   = (float*)alloc(sizeof(float) * B_GRAPHS * HD);
  float* v2B   = (float*)alloc(sizeof(float) * B_GRAPHS * HD);
  float* att1B = (float*)alloc(sizeof(float) * B_GRAPHS * HD);
  float* att2B = (float*)alloc(sizeof(float) * B_GRAPHS * HD);
  float* z1B   = (float*)alloc(sizeof(float) * B_GRAPHS * HD);
  float* z2B   = (float*)alloc(sizeof(float) * B_GRAPHS * (HD / 2));

  hipMemsetAsync(cnt, 0, sizeof(int) * N_NODES, stream);
  hipMemsetAsync(cur, 0, sizeof(int) * N_NODES, stream);

  const int SCAN_BLKS = (N_NODES + 1023) / 1024;  // 98
  ne_kernel<<<N_NODES * HID / 256, 256, 0, stream>>>(x, ne_W, ne_b, h, hbuf);
  wcvt_kernel<<<(L_LAYERS * HID * HID + 255) / 256, 256, 0, stream>>>(gat_W, wb);
  wprep_kernel<<<(L_LAYERS * 16 * 128 + 255) / 256, 256, 0, stream>>>(gat_W, gat_asrc, gat_adst, was8);
  hist_kernel<<<(E + 255) / 256, 256, 0, stream>>>(e_dst, cnt, E);
  scan1_kernel<<<SCAN_BLKS, 1024, 0, stream>>>(cnt, off, bsum, N_NODES);
  scan2_kernel<<<1, 64, 0, stream>>>(bsum, SCAN_BLKS);
  scan3_kernel<<<(N_NODES + 256) / 256, 256, 0, stream>>>(bsum, off, N_NODES, E);
  scatter_kernel<<<(E + 255) / 256, 256, 0, stream>>>(e_src, e_dst, off, cur, eadj, E);

  const unsigned EDGE_BLKS = (E + 255) / 256;
  for (int l = 0; l < L_LAYERS; ++l) {
    gat_xl_kernel<<<(N_NODES + 127) / 128, 256, 0, stream>>>(
        hbuf, wb + (size_t)l * HID * HID, was8 + (size_t)l * 16 * HID,
        xlp, esrc, edst);
    edgew_kernel<<<EDGE_BLKS, 256, 0, stream>>>(eadj, off, esrc, edst, qw, E);
    gat_agg_kernel<<<N_NODES / 4, 256, 0, stream>>>(
        xlp, esrc, edst, qw, off, eadj, gat_b + l * HID, ln_g + l * HID, ln_b + l * HID,
        h, hbuf);
  }
  pool_kernel<<<dim3(B_GRAPHS, 4), 256, 0, stream>>>(h, batch, pooled);

  // ---- head: 8 dependency levels, wave-per-output ----
  const float* a1_Wv = a1_Wi + 2 * HD * HD;
  const float* a1_bv = a1_bi + 2 * HD;
  const float* a2_Wv = a2_Wi + 2 * HD * HD;
  const float* a2_bv = a2_bi + 2 * HD;
  auto nblk = [](int waves) { return (unsigned)((waves + 3) / 4); };

  {
    int nw1 = B_GRAPHS * HD, nwT = nw1 + B_GRAPHS * HID;
    gemv2_kernel<<<nblk(nwT), 256, 0, stream>>>(
        seq_emb, SEQ_LEN, sp_W, sp_b, seqhB, HD, 8, SEQ_LEN, 0,
        pooled, HID, op1_W, op1_b, t1B, HID, 7, HID, 1, nw1, nwT);
  }
  {
    int nw1 = B_GRAPHS * HD, nwT = nw1 + B_GRAPHS * HID;
    gemv2_kernel<<<nblk(nwT), 256, 0, stream>>>(
        seqhB, HD, a2_Wv, a2_bv, v2B, HD, 8, HD, 0,
        t1B, HID, op2_W, op2_b, sembB, HID, 7, HID, 0, nw1, nwT);
  }
  {
    int nw1 = B_GRAPHS * HD, nwT = nw1 + B_GRAPHS * HD;
    gemv2_kernel<<<nblk(nwT), 256, 0, stream>>>(
        v2B, HD, a2_Wo, a2_bo, att2B, HD, 8, HD, 0,
        sembB, HID, stp_W, stp_b, strhB, HD, 8, HID, 0, nw1, nwT);
  }
  {
    int nwT = B_GRAPHS * HD;
    gemv2_kernel<<<nblk(nwT), 256, 0, stream>>>(
        strhB, HD, a1_Wv, a1_bv, v1B, HD, 8, HD, 0,
        nullptr, 0, nullptr, nullptr, nullptr, 0, 0, 0, 0, nwT, nwT);
  }
  {
    int nwT = B_GRAPHS * HD;
    gemv2_kernel<<<nblk(nwT), 256, 0, stream>>>(
        v1B, HD, a1_Wo, a1_bo, att1B, HD, 8, HD, 0,
        nullptr, 0, nullptr, nullptr, nullptr, 0, 0, 0, 0, nwT, nwT);
  }
  z1_kernel<<<nblk(B_GRAPHS * HD), 256, 0, stream>>>(att1B, att2B, seqhB, strhB, p1_W, p1_b, z1B);
  {
    int nwT = B_GRAPHS * (HD / 2);
    gemv2_kernel<<<nblk(nwT), 256, 0, stream>>>(
        z1B, HD, p2_W, p2_b, z2B, HD / 2, 7, HD, 1,
        nullptr, 0, nullptr, nullptr, nullptr, 0, 0, 0, 0, nwT, nwT);
  }
  {
    int nwT = B_GRAPHS;
    gemv2_kernel<<<nblk(nwT), 256, 0, stream>>>(
        z2B, HD / 2, p3_W, p3_b, (float*)d_out, 1, 0, HD / 2, 0,
        nullptr, 0, nullptr, nullptr, nullptr, 0, 0, 0, 0, nwT, nwT);
  }
}

// Round 9
// 620.161 us; speedup vs baseline: 1.1291x; 1.0386x over previous
//
#include <hip/hip_runtime.h>
#include <hip/hip_bf16.h>

#define N_NODES 100000
#define NFEAT 9
#define HID 128
#define B_GRAPHS 64
#define SEQ_LEN 768
#define HD 256
#define L_LAYERS 4
#define LN_EPS 1e-5f

typedef __attribute__((ext_vector_type(8))) short short8;
typedef __attribute__((ext_vector_type(4))) float f32x4;

__device__ __forceinline__ float lrelu(float v) { return v > 0.f ? v : 0.2f * v; }

__device__ __forceinline__ float wave_sum64(float x) {
#pragma unroll
  for (int o = 32; o >= 1; o >>= 1) x += __shfl_xor(x, o, 64);
  return x;
}

__device__ __forceinline__ unsigned short bf16r(float v) {
  unsigned int u = __float_as_uint(v);
  return (unsigned short)((u + 0x7fffu + ((u >> 16) & 1u)) >> 16);
}
// pack: low16 = bf16(lo), high16 = bf16(hi)
__device__ __forceinline__ unsigned int bf16pair(float lo, float hi) {
  unsigned int ul = __float_as_uint(lo);
  unsigned int uh = __float_as_uint(hi);
  ul = (ul + 0x7fffu + ((ul >> 16) & 1u)) >> 16;
  uh = (uh + 0x7fffu + ((uh >> 16) & 1u)) & 0xffff0000u;
  return ul | uh;
}
__device__ __forceinline__ float bflo(unsigned int u) { return __uint_as_float(u << 16); }
__device__ __forceinline__ float bfhi(unsigned int u) { return __uint_as_float(u & 0xffff0000u); }

// h = relu(x @ ne_W.T + ne_b) -> bf16 hb only
__global__ __launch_bounds__(256) void ne_kernel(const float* __restrict__ x,
                                                 const float* __restrict__ W,
                                                 const float* __restrict__ b,
                                                 unsigned short* __restrict__ hb) {
  int idx = blockIdx.x * 256 + threadIdx.x;
  int n = idx >> 7, c = idx & 127;
  const float* xr = x + n * NFEAT;
  const float* wr = W + c * NFEAT;
  float acc = b[c];
#pragma unroll
  for (int k = 0; k < NFEAT; ++k) acc += xr[k] * wr[k];
  acc = fmaxf(acc, 0.f);
  hb[idx] = bf16r(acc);
}

// convert all L layers of gat_W to bf16
__global__ __launch_bounds__(256) void wcvt_kernel(const float* __restrict__ W,
                                                   unsigned short* __restrict__ wb) {
  int idx = blockIdx.x * 256 + threadIdx.x;
  if (idx < L_LAYERS * HID * HID) wb[idx] = bf16r(W[idx]);
}

// was8[l][j][k]: j<4: sum_c W[l][j*32+c][k]*asrc[l][j*32+c]; j in 4..7: adst; j>=8: 0
__global__ __launch_bounds__(256) void wprep_kernel(const float* __restrict__ W,
                                                    const float* __restrict__ asrc,
                                                    const float* __restrict__ adst,
                                                    unsigned short* __restrict__ was8) {
  int t = blockIdx.x * 256 + threadIdx.x;  // L*16*128
  if (t >= L_LAYERS * 16 * 128) return;
  int l = t >> 11;
  int rem = t & 2047;
  int j = rem >> 7;
  int k = rem & 127;
  float sum = 0.f;
  if (j < 8) {
    int head = j & 3;
    const float* a = (j < 4) ? (asrc + l * HID + head * 32) : (adst + l * HID + head * 32);
    const float* Wl = W + (size_t)l * HID * HID + (size_t)(head * 32) * HID + k;
#pragma unroll 8
    for (int c = 0; c < 32; ++c) sum += Wl[(size_t)c * HID] * a[c];
  }
  was8[t] = bf16r(sum);
}

__global__ __launch_bounds__(256) void hist_kernel(const int* __restrict__ dst,
                                                   int* __restrict__ cnt, int E) {
  int i = blockIdx.x * 256 + threadIdx.x;
  if (i < E) atomicAdd(&cnt[dst[i]], 1);
}

// hierarchical exclusive scan
__global__ __launch_bounds__(1024) void scan1_kernel(const int* __restrict__ cnt,
                                                     int* __restrict__ off,
                                                     int* __restrict__ bsum, int n) {
  __shared__ int ws[16];
  __shared__ int wx[16];
  int tid = threadIdx.x, lane = tid & 63, w = tid >> 6;
  int i = blockIdx.x * 1024 + tid;
  int v = (i < n) ? cnt[i] : 0;
  int x = v;
#pragma unroll
  for (int o = 1; o < 64; o <<= 1) {
    int t = __shfl_up(x, o, 64);
    if (lane >= o) x += t;
  }
  if (lane == 63) ws[w] = x;
  __syncthreads();
  if (tid == 0) {
    int r = 0;
#pragma unroll
    for (int j = 0; j < 16; ++j) { int t = ws[j]; wx[j] = r; r += t; }
    bsum[blockIdx.x] = r;
  }
  __syncthreads();
  if (i < n) off[i] = wx[w] + x - v;
}

__global__ void scan2_kernel(int* __restrict__ bsum, int nb) {
  int lane = threadIdx.x;
  int i0 = lane * 2, i1 = i0 + 1;
  int a = (i0 < nb) ? bsum[i0] : 0;
  int b = (i1 < nb) ? bsum[i1] : 0;
  int s = a + b, x = s;
#pragma unroll
  for (int o = 1; o < 64; o <<= 1) {
    int t = __shfl_up(x, o, 64);
    if (lane >= o) x += t;
  }
  int excl = x - s;
  if (i0 < nb) bsum[i0] = excl;
  if (i1 < nb) bsum[i1] = excl + a;
}

__global__ __launch_bounds__(256) void scan3_kernel(const int* __restrict__ bsum,
                                                    int* __restrict__ off, int n, int total) {
  int i = blockIdx.x * 256 + threadIdx.x;
  if (i < n) off[i] += bsum[i >> 10];
  else if (i == n) off[i] = total;
}

__global__ __launch_bounds__(256) void scatter_kernel(const int* __restrict__ src,
                                                      const int* __restrict__ dst,
                                                      const int* __restrict__ off,
                                                      int* __restrict__ cur,
                                                      int* __restrict__ eadj, int E) {
  int i = blockIdx.x * 256 + threadIdx.x;
  if (i < E) {
    int d = dst[i];
    int pos = atomicAdd(&cur[d], 1);
    eadj[off[d] + pos] = src[i];
  }
}

// per-edge softmax weights packed bf16x4; dst recovered by binary search in off
__global__ __launch_bounds__(256) void edgew_kernel(const int* __restrict__ eadj,
                                                    const int* __restrict__ off,
                                                    const float* __restrict__ esrc,
                                                    const float* __restrict__ edst,
                                                    uint2* __restrict__ qw, int E) {
  int j = blockIdx.x * 256 + threadIdx.x;
  if (j >= E) return;
  int s = eadj[j];
  int lo = 0, hi = N_NODES;  // invariant: off[lo] <= j < off[hi]
  while (lo + 1 < hi) {
    int mid = (lo + hi) >> 1;
    if (off[mid] <= j) lo = mid; else hi = mid;
  }
  const float4 es = *(const float4*)(esrc + (size_t)s * 4);
  const float4 ed = *(const float4*)(edst + (size_t)lo * 4);
  float q0 = __expf(lrelu(es.x + ed.x));
  float q1 = __expf(lrelu(es.y + ed.y));
  float q2 = __expf(lrelu(es.z + ed.z));
  float q3 = __expf(lrelu(es.w + ed.w));
  qw[j] = make_uint2(bf16pair(q0, q1), bf16pair(q2, q3));
}

// xl = h @ W.T via bf16 MFMA. 128 rows/block, 4 waves (32 rows each), full 128 cols.
// Logits computed with one extra MFMA B-operand (was8), no shuffles.
__global__ __launch_bounds__(256) void gat_xl_kernel(const unsigned short* __restrict__ hb,
                                                     const unsigned short* __restrict__ wb,
                                                     const unsigned short* __restrict__ wasb,
                                                     unsigned int* __restrict__ xlp,
                                                     float* __restrict__ esrc,
                                                     float* __restrict__ edst) {
  __shared__ unsigned short Wl[128][136];  // +8 pad: 2-way bank alias only
  const int tid = threadIdx.x;
  const int lane = tid & 63;
  const int wv = tid >> 6;
  const int base = blockIdx.x * 128;
  const int l15 = lane & 15;
  const int lg = lane >> 4;  // 0..3

  // stage W (bf16) into LDS
#pragma unroll
  for (int t = 0; t < 8; ++t) {
    int f8 = tid + t * 256;          // 2048 chunks of 8 ushorts
    int row = f8 >> 4, c8 = (f8 & 15) * 8;
    uint4 v = *(const uint4*)(wb + row * HID + c8);
    *(uint4*)&Wl[row][c8] = v;
  }
  __syncthreads();

  f32x4 acc[2][8];
  f32x4 acc_e[2];
#pragma unroll
  for (int rb = 0; rb < 2; ++rb) {
#pragma unroll
    for (int nb = 0; nb < 8; ++nb) acc[rb][nb] = (f32x4){0.f, 0.f, 0.f, 0.f};
    acc_e[rb] = (f32x4){0.f, 0.f, 0.f, 0.f};
  }

  int n0 = base + wv * 32 + l15;
  int n1 = n0 + 16;
  if (n0 >= N_NODES) n0 = N_NODES - 1;
  if (n1 >= N_NODES) n1 = N_NODES - 1;
  const size_t rowA0 = (size_t)n0 * HID;
  const size_t rowA1 = (size_t)n1 * HID;

#pragma unroll
  for (int kc = 0; kc < 4; ++kc) {
    const int kb = kc * 32 + lg * 8;
    short8 a0 = *(const short8*)(hb + rowA0 + kb);
    short8 a1 = *(const short8*)(hb + rowA1 + kb);
    short8 efrag = *(const short8*)(wasb + l15 * HID + kb);
    acc_e[0] = __builtin_amdgcn_mfma_f32_16x16x32_bf16(a0, efrag, acc_e[0], 0, 0, 0);
    acc_e[1] = __builtin_amdgcn_mfma_f32_16x16x32_bf16(a1, efrag, acc_e[1], 0, 0, 0);
#pragma unroll
    for (int nb = 0; nb < 8; ++nb) {
      short8 bfrag = *(const short8*)&Wl[nb * 16 + l15][kb];
      acc[0][nb] = __builtin_amdgcn_mfma_f32_16x16x32_bf16(a0, bfrag, acc[0][nb], 0, 0, 0);
      acc[1][nb] = __builtin_amdgcn_mfma_f32_16x16x32_bf16(a1, bfrag, acc[1][nb], 0, 0, 0);
    }
  }

#pragma unroll
  for (int rb = 0; rb < 2; ++rb) {
#pragma unroll
    for (int r = 0; r < 4; ++r) {
      int node = base + wv * 32 + rb * 16 + lg * 4 + r;
      if (node < N_NODES) {
#pragma unroll
        for (int nb = 0; nb < 4; ++nb) {
          unsigned int pk = bf16pair(acc[rb][nb][r], acc[rb][nb + 4][r]);
          xlp[(size_t)node * 64 + nb * 16 + l15] = pk;
        }
        float ev = acc_e[rb][r];
        if (l15 < 4) esrc[node * 4 + l15] = ev;
        else if (l15 < 8) edst[node * 4 + (l15 - 4)] = ev;
      }
    }
  }
}

// single-pass softmax aggregation; per-edge bf16 weights precomputed (qw).
// Wave per node; 4-edge software pipeline. Residual lives in bf16 hb.
__global__ __launch_bounds__(256) void gat_agg_kernel(const unsigned int* __restrict__ xlp,
                                                      const float* __restrict__ esrc,
                                                      const float* __restrict__ edst,
                                                      const uint2* __restrict__ qw,
                                                      const int* __restrict__ off,
                                                      const int* __restrict__ eadj,
                                                      const float* __restrict__ gbias,
                                                      const float* __restrict__ lng,
                                                      const float* __restrict__ lnb,
                                                      unsigned short* __restrict__ hb) {
  const int tid = threadIdx.x;
  const int lane = tid & 63;
  const int i = blockIdx.x * 4 + (tid >> 6);
  const int hd0 = lane >> 5;

  const float4 ed = *(const float4*)(edst + (size_t)i * 4);
  const float4 e0 = *(const float4*)(esrc + (size_t)i * 4);
  float w0 = __expf(lrelu(e0.x + ed.x));
  float w1 = __expf(lrelu(e0.y + ed.y));
  float w2 = __expf(lrelu(e0.z + ed.z));
  float w3 = __expf(lrelu(e0.w + ed.w));
  float sA = (hd0 == 0 ? w0 : w1);
  float sB = (hd0 == 0 ? w2 : w3);
  const unsigned int* xp = xlp + lane;
  const unsigned int vi = xp[(size_t)i * 64];
  float accA = bflo(vi) * sA;
  float accB = bfhi(vi) * sB;
  const int beg = off[i], end = off[i + 1];
  int j = beg;
  for (; j + 4 <= end; j += 4) {
    const int sa = eadj[j + 0];
    const int sb = eadj[j + 1];
    const int sc = eadj[j + 2];
    const int sd = eadj[j + 3];
    const uint2 Qa = qw[j + 0];
    const uint2 Qb = qw[j + 1];
    const uint2 Qc = qw[j + 2];
    const uint2 Qd = qw[j + 3];
    const unsigned int va = xp[(size_t)sa * 64];
    const unsigned int vb = xp[(size_t)sb * 64];
    const unsigned int vc = xp[(size_t)sc * 64];
    const unsigned int vd = xp[(size_t)sd * 64];
    float qAa = hd0 == 0 ? bflo(Qa.x) : bfhi(Qa.x);
    float qBa = hd0 == 0 ? bflo(Qa.y) : bfhi(Qa.y);
    float qAb = hd0 == 0 ? bflo(Qb.x) : bfhi(Qb.x);
    float qBb = hd0 == 0 ? bflo(Qb.y) : bfhi(Qb.y);
    float qAc = hd0 == 0 ? bflo(Qc.x) : bfhi(Qc.x);
    float qBc = hd0 == 0 ? bflo(Qc.y) : bfhi(Qc.y);
    float qAd = hd0 == 0 ? bflo(Qd.x) : bfhi(Qd.x);
    float qBd = hd0 == 0 ? bflo(Qd.y) : bfhi(Qd.y);
    sA += qAa + qAb + qAc + qAd;
    sB += qBa + qBb + qBc + qBd;
    accA = fmaf(bflo(va), qAa, accA);
    accA = fmaf(bflo(vb), qAb, accA);
    accA = fmaf(bflo(vc), qAc, accA);
    accA = fmaf(bflo(vd), qAd, accA);
    accB = fmaf(bfhi(va), qBa, accB);
    accB = fmaf(bfhi(vb), qBb, accB);
    accB = fmaf(bfhi(vc), qBc, accB);
    accB = fmaf(bfhi(vd), qBd, accB);
  }
  for (; j < end; ++j) {
    const int sc = eadj[j];
    const uint2 Q = qw[j];
    const unsigned int v = xp[(size_t)sc * 64];
    float qA = hd0 == 0 ? bflo(Q.x) : bfhi(Q.x);
    float qB = hd0 == 0 ? bflo(Q.y) : bfhi(Q.y);
    sA += qA;
    sB += qB;
    accA = fmaf(bflo(v), qA, accA);
    accB = fmaf(bfhi(v), qB, accB);
  }
  float o0 = accA / (sA + 1e-16f) + gbias[lane];
  float o1 = accB / (sB + 1e-16f) + gbias[lane + 64];
  float mu = wave_sum64(o0 + o1) * (1.f / 128.f);
  float d0 = o0 - mu, d1 = o1 - mu;
  float var = wave_sum64(d0 * d0 + d1 * d1) * (1.f / 128.f);
  float r = rsqrtf(var + LN_EPS);
  float hn0 = fmaxf(d0 * r * lng[lane] + lnb[lane], 0.f);
  float hn1 = fmaxf(d1 * r * lng[lane + 64] + lnb[lane + 64], 0.f);
  unsigned short h0 = hb[(size_t)i * HID + lane];
  unsigned short h1 = hb[(size_t)i * HID + 64 + lane];
  float nh0 = __uint_as_float((unsigned int)h0 << 16) + hn0;
  float nh1 = __uint_as_float((unsigned int)h1 << 16) + hn1;
  hb[(size_t)i * HID + lane] = bf16r(nh0);
  hb[(size_t)i * HID + 64 + lane] = bf16r(nh1);
}

__device__ __forceinline__ int lower_bound_dev(const int* a, int n, int v) {
  int lo = 0, hi = n;
  while (lo < hi) {
    int mid = (lo + hi) >> 1;
    if (a[mid] < v) lo = mid + 1; else hi = mid;
  }
  return lo;
}

// per-batch mean pool from bf16 hb; grid (B, 4)
__global__ __launch_bounds__(256) void pool_kernel(const unsigned short* __restrict__ hb,
                                                   const int* __restrict__ batch,
                                                   float* __restrict__ pooled) {
  __shared__ float red[256];
  int b = blockIdx.x, tid = threadIdx.x;
  int start = lower_bound_dev(batch, N_NODES, b);
  int end = lower_bound_dev(batch, N_NODES, b + 1);
  int cl = tid & 31, g = tid >> 5;
  int c = cl + blockIdx.y * 32;
  float acc = 0.f;
  for (int n = start + g; n < end; n += 8)
    acc += __uint_as_float((unsigned int)hb[(size_t)n * HID + c] << 16);
  red[tid] = acc;
  __syncthreads();
  if (g == 0) {
    float tot = 0.f;
#pragma unroll
    for (int k = 0; k < 8; ++k) tot += red[cl + 32 * k];
    float cntf = fmaxf((float)(end - start), 1.f);
    pooled[b * HID + c] = tot / cntf;
  }
}

// One wave per output element (m,c); lane-split K; two independent fused stages.
__global__ __launch_bounds__(256) void gemv2_kernel(
    const float* __restrict__ A1, int lda1, const float* __restrict__ W1,
    const float* __restrict__ b1, float* __restrict__ O1, int ldo1,
    int sh1, int K1, int relu1,
    const float* __restrict__ A2, int lda2, const float* __restrict__ W2,
    const float* __restrict__ b2, float* __restrict__ O2, int ldo2,
    int sh2, int K2, int relu2, int nw1, int nwTot) {
  int gw = (blockIdx.x * 256 + threadIdx.x) >> 6;
  int lane = threadIdx.x & 63;
  if (gw >= nwTot) return;
  const float *A, *W, *b;
  float* O;
  int lda, ldo, K, relu, m, c;
  if (gw < nw1) {
    A = A1; W = W1; b = b1; O = O1; lda = lda1; ldo = ldo1; K = K1; relu = relu1;
    m = gw >> sh1; c = gw & ((1 << sh1) - 1);
  } else {
    int g2 = gw - nw1;
    A = A2; W = W2; b = b2; O = O2; lda = lda2; ldo = ldo2; K = K2; relu = relu2;
    m = g2 >> sh2; c = g2 & ((1 << sh2) - 1);
  }
  const float* a = A + (size_t)m * lda;
  const float* w = W + (size_t)c * K;
  float acc = 0.f;
  for (int k = lane * 2; k < K; k += 128) {
    float2 av = *(const float2*)(a + k);
    float2 wv = *(const float2*)(w + k);
    acc += av.x * wv.x + av.y * wv.y;
  }
  acc = wave_sum64(acc);
  if (lane == 0) {
    acc += b[c];
    if (relu) acc = fmaxf(acc, 0.f);
    O[(size_t)m * ldo + c] = acc;
  }
}

// z1 = relu([att1|att2|seqh|strh] @ p1_W.T + p1_b); wave per (m,c)
__global__ __launch_bounds__(256) void z1_kernel(const float* __restrict__ att1,
                                                 const float* __restrict__ att2,
                                                 const float* __restrict__ seqh,
                                                 const float* __restrict__ strh,
                                                 const float* __restrict__ p1_W,
                                                 const float* __restrict__ p1_b,
                                                 float* __restrict__ z1) {
  int gw = (blockIdx.x * 256 + threadIdx.x) >> 6;
  int lane = threadIdx.x & 63;
  int m = gw >> 8, c = gw & 255;
  const float* segs[4] = {att1 + m * HD, att2 + m * HD, seqh + m * HD, strh + m * HD};
  const float* w = p1_W + (size_t)c * (4 * HD);
  float acc = 0.f;
#pragma unroll
  for (int s = 0; s < 4; ++s) {
    const float* a = segs[s];
#pragma unroll
    for (int k = lane * 2; k < HD; k += 128) {
      float2 av = *(const float2*)(a + k);
      float2 wv = *(const float2*)(w + s * HD + k);
      acc += av.x * wv.x + av.y * wv.y;
    }
  }
  acc = wave_sum64(acc);
  if (lane == 0) z1[m * HD + c] = fmaxf(acc + p1_b[c], 0.f);
}

extern "C" void kernel_launch(void* const* d_in, const int* in_sizes, int n_in,
                              void* d_out, int out_size, void* d_ws, size_t ws_size,
                              hipStream_t stream) {
  const float* seq_emb = (const float*)d_in[0];
  const float* x       = (const float*)d_in[1];
  const int* eidx      = (const int*)d_in[2];
  const int* batch     = (const int*)d_in[3];
  const float* ne_W = (const float*)d_in[4];
  const float* ne_b = (const float*)d_in[5];
  const float* gat_W = (const float*)d_in[6];
  const float* gat_asrc = (const float*)d_in[7];
  const float* gat_adst = (const float*)d_in[8];
  const float* gat_b = (const float*)d_in[9];
  const float* ln_g = (const float*)d_in[10];
  const float* ln_b = (const float*)d_in[11];
  const float* op1_W = (const float*)d_in[12];
  const float* op1_b = (const float*)d_in[13];
  const float* op2_W = (const float*)d_in[14];
  const float* op2_b = (const float*)d_in[15];
  const float* sp_W = (const float*)d_in[16];
  const float* sp_b = (const float*)d_in[17];
  const float* stp_W = (const float*)d_in[18];
  const float* stp_b = (const float*)d_in[19];
  const float* a1_Wi = (const float*)d_in[20];
  const float* a1_bi = (const float*)d_in[21];
  const float* a1_Wo = (const float*)d_in[22];
  const float* a1_bo = (const float*)d_in[23];
  const float* a2_Wi = (const float*)d_in[24];
  const float* a2_bi = (const float*)d_in[25];
  const float* a2_Wo = (const float*)d_in[26];
  const float* a2_bo = (const float*)d_in[27];
  const float* p1_W = (const float*)d_in[28];
  const float* p1_b = (const float*)d_in[29];
  const float* p2_W = (const float*)d_in[30];
  const float* p2_b = (const float*)d_in[31];
  const float* p3_W = (const float*)d_in[32];
  const float* p3_b = (const float*)d_in[33];

  const int E = in_sizes[2] / 2;
  const int* e_src = eidx;
  const int* e_dst = eidx + E;

  char* p = (char*)d_ws;
  auto alloc = [&](size_t bytes) -> void* {
    void* r = p;
    p += (bytes + 255) & ~(size_t)255;
    return r;
  };
  unsigned short* hbuf = (unsigned short*)alloc(sizeof(unsigned short) * (size_t)N_NODES * HID);
  unsigned short* wb   = (unsigned short*)alloc(sizeof(unsigned short) * L_LAYERS * HID * HID);
  unsigned short* was8 = (unsigned short*)alloc(sizeof(unsigned short) * L_LAYERS * 16 * HID);
  unsigned int* xlp = (unsigned int*)alloc(sizeof(unsigned int) * (size_t)N_NODES * 64);
  float* esrc = (float*)alloc(sizeof(float) * (size_t)N_NODES * 4);
  float* edst = (float*)alloc(sizeof(float) * (size_t)N_NODES * 4);
  int* cnt    = (int*)alloc(sizeof(int) * N_NODES);
  int* cur    = (int*)alloc(sizeof(int) * N_NODES);
  int* off    = (int*)alloc(sizeof(int) * (N_NODES + 1));
  int* eadj   = (int*)alloc(sizeof(int) * (size_t)E);
  uint2* qw   = (uint2*)alloc(sizeof(uint2) * (size_t)E);
  int* bsum   = (int*)alloc(sizeof(int) * 128);
  float* pooled = (float*)alloc(sizeof(float) * B_GRAPHS * HID);
  float* t1B   = (float*)alloc(sizeof(float) * B_GRAPHS * HID);
  float* sembB = (float*)alloc(sizeof(float) * B_GRAPHS * HID);
  float* seqhB = (float*)alloc(sizeof(float) * B_GRAPHS * HD);
  float* strhB = (float*)alloc(sizeof(float) * B_GRAPHS * HD);
  float* v1B   = (float*)alloc(sizeof(float) * B_GRAPHS * HD);
  float* v2B   = (float*)alloc(sizeof(float) * B_GRAPHS * HD);
  float* att1B = (float*)alloc(sizeof(float) * B_GRAPHS * HD);
  float* att2B = (float*)alloc(sizeof(float) * B_GRAPHS * HD);
  float* z1B   = (float*)alloc(sizeof(float) * B_GRAPHS * HD);
  float* z2B   = (float*)alloc(sizeof(float) * B_GRAPHS * (HD / 2));

  hipMemsetAsync(cnt, 0, sizeof(int) * N_NODES, stream);
  hipMemsetAsync(cur, 0, sizeof(int) * N_NODES, stream);

  const int SCAN_BLKS = (N_NODES + 1023) / 1024;  // 98
  ne_kernel<<<N_NODES * HID / 256, 256, 0, stream>>>(x, ne_W, ne_b, hbuf);
  wcvt_kernel<<<(L_LAYERS * HID * HID + 255) / 256, 256, 0, stream>>>(gat_W, wb);
  wprep_kernel<<<(L_LAYERS * 16 * 128 + 255) / 256, 256, 0, stream>>>(gat_W, gat_asrc, gat_adst, was8);
  hist_kernel<<<(E + 255) / 256, 256, 0, stream>>>(e_dst, cnt, E);
  scan1_kernel<<<SCAN_BLKS, 1024, 0, stream>>>(cnt, off, bsum, N_NODES);
  scan2_kernel<<<1, 64, 0, stream>>>(bsum, SCAN_BLKS);
  scan3_kernel<<<(N_NODES + 256) / 256, 256, 0, stream>>>(bsum, off, N_NODES, E);
  scatter_kernel<<<(E + 255) / 256, 256, 0, stream>>>(e_src, e_dst, off, cur, eadj, E);

  const unsigned EDGE_BLKS = (E + 255) / 256;
  for (int l = 0; l < L_LAYERS; ++l) {
    gat_xl_kernel<<<(N_NODES + 127) / 128, 256, 0, stream>>>(
        hbuf, wb + (size_t)l * HID * HID, was8 + (size_t)l * 16 * HID,
        xlp, esrc, edst);
    edgew_kernel<<<EDGE_BLKS, 256, 0, stream>>>(eadj, off, esrc, edst, qw, E);
    gat_agg_kernel<<<N_NODES / 4, 256, 0, stream>>>(
        xlp, esrc, edst, qw, off, eadj, gat_b + l * HID, ln_g + l * HID, ln_b + l * HID,
        hbuf);
  }
  pool_kernel<<<dim3(B_GRAPHS, 4), 256, 0, stream>>>(hbuf, batch, pooled);

  // ---- head: 8 dependency levels, wave-per-output ----
  const float* a1_Wv = a1_Wi + 2 * HD * HD;
  const float* a1_bv = a1_bi + 2 * HD;
  const float* a2_Wv = a2_Wi + 2 * HD * HD;
  const float* a2_bv = a2_bi + 2 * HD;
  auto nblk = [](int waves) { return (unsigned)((waves + 3) / 4); };

  {
    int nw1 = B_GRAPHS * HD, nwT = nw1 + B_GRAPHS * HID;
    gemv2_kernel<<<nblk(nwT), 256, 0, stream>>>(
        seq_emb, SEQ_LEN, sp_W, sp_b, seqhB, HD, 8, SEQ_LEN, 0,
        pooled, HID, op1_W, op1_b, t1B, HID, 7, HID, 1, nw1, nwT);
  }
  {
    int nw1 = B_GRAPHS * HD, nwT = nw1 + B_GRAPHS * HID;
    gemv2_kernel<<<nblk(nwT), 256, 0, stream>>>(
        seqhB, HD, a2_Wv, a2_bv, v2B, HD, 8, HD, 0,
        t1B, HID, op2_W, op2_b, sembB, HID, 7, HID, 0, nw1, nwT);
  }
  {
    int nw1 = B_GRAPHS * HD, nwT = nw1 + B_GRAPHS * HD;
    gemv2_kernel<<<nblk(nwT), 256, 0, stream>>>(
        v2B, HD, a2_Wo, a2_bo, att2B, HD, 8, HD, 0,
        sembB, HID, stp_W, stp_b, strhB, HD, 8, HID, 0, nw1, nwT);
  }
  {
    int nwT = B_GRAPHS * HD;
    gemv2_kernel<<<nblk(nwT), 256, 0, stream>>>(
        strhB, HD, a1_Wv, a1_bv, v1B, HD, 8, HD, 0,
        nullptr, 0, nullptr, nullptr, nullptr, 0, 0, 0, 0, nwT, nwT);
  }
  {
    int nwT = B_GRAPHS * HD;
    gemv2_kernel<<<nblk(nwT), 256, 0, stream>>>(
        v1B, HD, a1_Wo, a1_bo, att1B, HD, 8, HD, 0,
        nullptr, 0, nullptr, nullptr, nullptr, 0, 0, 0, 0, nwT, nwT);
  }
  z1_kernel<<<nblk(B_GRAPHS * HD), 256, 0, stream>>>(att1B, att2B, seqhB, strhB, p1_W, p1_b, z1B);
  {
    int nwT = B_GRAPHS * (HD / 2);
    gemv2_kernel<<<nblk(nwT), 256, 0, stream>>>(
        z1B, HD, p2_W, p2_b, z2B, HD / 2, 7, HD, 1,
        nullptr, 0, nullptr, nullptr, nullptr, 0, 0, 0, 0, nwT, nwT);
  }
  {
    int nwT = B_GRAPHS;
    gemv2_kernel<<<nblk(nwT), 256, 0, stream>>>(
        z2B, HD / 2, p3_W, p3_b, (float*)d_out, 1, 0, HD / 2, 0,
        nullptr, 0, nullptr, nullptr, nullptr, 0, 0, 0, 0, nwT, nwT);
  }
}

// Round 10
// 606.804 us; speedup vs baseline: 1.1539x; 1.0220x over previous
//
#include <hip/hip_runtime.h>
#include <hip/hip_bf16.h>

#define N_NODES 100000
#define NFEAT 9
#define HID 128
#define B_GRAPHS 64
#define SEQ_LEN 768
#define HD 256
#define L_LAYERS 4
#define LN_EPS 1e-5f

typedef __attribute__((ext_vector_type(8))) short short8;
typedef __attribute__((ext_vector_type(4))) float f32x4;

__device__ __forceinline__ float lrelu(float v) { return v > 0.f ? v : 0.2f * v; }

__device__ __forceinline__ float wave_sum64(float x) {
#pragma unroll
  for (int o = 32; o >= 1; o >>= 1) x += __shfl_xor(x, o, 64);
  return x;
}

__device__ __forceinline__ unsigned short bf16r(float v) {
  unsigned int u = __float_as_uint(v);
  return (unsigned short)((u + 0x7fffu + ((u >> 16) & 1u)) >> 16);
}
// pack: low16 = bf16(lo), high16 = bf16(hi)
__device__ __forceinline__ unsigned int bf16pair(float lo, float hi) {
  unsigned int ul = __float_as_uint(lo);
  unsigned int uh = __float_as_uint(hi);
  ul = (ul + 0x7fffu + ((ul >> 16) & 1u)) >> 16;
  uh = (uh + 0x7fffu + ((uh >> 16) & 1u)) & 0xffff0000u;
  return ul | uh;
}
__device__ __forceinline__ float bflo(unsigned int u) { return __uint_as_float(u << 16); }
__device__ __forceinline__ float bfhi(unsigned int u) { return __uint_as_float(u & 0xffff0000u); }

// h = relu(x @ ne_W.T + ne_b) -> bf16 hb only
__global__ __launch_bounds__(256) void ne_kernel(const float* __restrict__ x,
                                                 const float* __restrict__ W,
                                                 const float* __restrict__ b,
                                                 unsigned short* __restrict__ hb) {
  int idx = blockIdx.x * 256 + threadIdx.x;
  int n = idx >> 7, c = idx & 127;
  const float* xr = x + n * NFEAT;
  const float* wr = W + c * NFEAT;
  float acc = b[c];
#pragma unroll
  for (int k = 0; k < NFEAT; ++k) acc += xr[k] * wr[k];
  acc = fmaxf(acc, 0.f);
  hb[idx] = bf16r(acc);
}

// convert all L layers of gat_W to bf16
__global__ __launch_bounds__(256) void wcvt_kernel(const float* __restrict__ W,
                                                   unsigned short* __restrict__ wb) {
  int idx = blockIdx.x * 256 + threadIdx.x;
  if (idx < L_LAYERS * HID * HID) wb[idx] = bf16r(W[idx]);
}

// was8[l][j][k]: j<4: sum_c W[l][j*32+c][k]*asrc[l][j*32+c]; j in 4..7: adst; j>=8: 0
__global__ __launch_bounds__(256) void wprep_kernel(const float* __restrict__ W,
                                                    const float* __restrict__ asrc,
                                                    const float* __restrict__ adst,
                                                    unsigned short* __restrict__ was8) {
  int t = blockIdx.x * 256 + threadIdx.x;  // L*16*128
  if (t >= L_LAYERS * 16 * 128) return;
  int l = t >> 11;
  int rem = t & 2047;
  int j = rem >> 7;
  int k = rem & 127;
  float sum = 0.f;
  if (j < 8) {
    int head = j & 3;
    const float* a = (j < 4) ? (asrc + l * HID + head * 32) : (adst + l * HID + head * 32);
    const float* Wl = W + (size_t)l * HID * HID + (size_t)(head * 32) * HID + k;
#pragma unroll 8
    for (int c = 0; c < 32; ++c) sum += Wl[(size_t)c * HID] * a[c];
  }
  was8[t] = bf16r(sum);
}

__global__ __launch_bounds__(256) void hist_kernel(const int* __restrict__ dst,
                                                   int* __restrict__ cnt, int E) {
  int i = blockIdx.x * 256 + threadIdx.x;
  if (i < E) atomicAdd(&cnt[dst[i]], 1);
}

// hierarchical exclusive scan
__global__ __launch_bounds__(1024) void scan1_kernel(const int* __restrict__ cnt,
                                                     int* __restrict__ off,
                                                     int* __restrict__ bsum, int n) {
  __shared__ int ws[16];
  __shared__ int wx[16];
  int tid = threadIdx.x, lane = tid & 63, w = tid >> 6;
  int i = blockIdx.x * 1024 + tid;
  int v = (i < n) ? cnt[i] : 0;
  int x = v;
#pragma unroll
  for (int o = 1; o < 64; o <<= 1) {
    int t = __shfl_up(x, o, 64);
    if (lane >= o) x += t;
  }
  if (lane == 63) ws[w] = x;
  __syncthreads();
  if (tid == 0) {
    int r = 0;
#pragma unroll
    for (int j = 0; j < 16; ++j) { int t = ws[j]; wx[j] = r; r += t; }
    bsum[blockIdx.x] = r;
  }
  __syncthreads();
  if (i < n) off[i] = wx[w] + x - v;
}

__global__ void scan2_kernel(int* __restrict__ bsum, int nb) {
  int lane = threadIdx.x;
  int i0 = lane * 2, i1 = i0 + 1;
  int a = (i0 < nb) ? bsum[i0] : 0;
  int b = (i1 < nb) ? bsum[i1] : 0;
  int s = a + b, x = s;
#pragma unroll
  for (int o = 1; o < 64; o <<= 1) {
    int t = __shfl_up(x, o, 64);
    if (lane >= o) x += t;
  }
  int excl = x - s;
  if (i0 < nb) bsum[i0] = excl;
  if (i1 < nb) bsum[i1] = excl + a;
}

__global__ __launch_bounds__(256) void scan3_kernel(const int* __restrict__ bsum,
                                                    int* __restrict__ off, int n, int total) {
  int i = blockIdx.x * 256 + threadIdx.x;
  if (i < n) off[i] += bsum[i >> 10];
  else if (i == n) off[i] = total;
}

// stores PRE-SCALED src offsets (src*64 dwords) for cheap gathers downstream
__global__ __launch_bounds__(256) void scatter_kernel(const int* __restrict__ src,
                                                      const int* __restrict__ dst,
                                                      const int* __restrict__ off,
                                                      int* __restrict__ cur,
                                                      int* __restrict__ eadj, int E) {
  int i = blockIdx.x * 256 + threadIdx.x;
  if (i < E) {
    int d = dst[i];
    int pos = atomicAdd(&cur[d], 1);
    eadj[off[d] + pos] = src[i] << 6;
  }
}

__device__ __forceinline__ int csr_row_of(const int* __restrict__ off, int j, int lo, int hi) {
  // invariant: off[lo] <= j < off[hi]
  while (lo + 1 < hi) {
    int mid = (lo + hi) >> 1;
    if (off[mid] <= j) lo = mid; else hi = mid;
  }
  return lo;
}

// per-edge softmax weights packed bf16x4; dst via block-seeded binary search
__global__ __launch_bounds__(256) void edgew_kernel(const int* __restrict__ eadj,
                                                    const int* __restrict__ off,
                                                    const float* __restrict__ esrc,
                                                    const float* __restrict__ edst,
                                                    uint2* __restrict__ qw, int E) {
  __shared__ int sLo, sHi;
  int tid = threadIdx.x;
  int j = blockIdx.x * 256 + tid;
  int jlast = min(blockIdx.x * 256 + 255, E - 1);
  if (tid == 0) sLo = csr_row_of(off, blockIdx.x * 256, 0, N_NODES);
  if (tid == 255) sHi = csr_row_of(off, jlast, 0, N_NODES) + 1;
  __syncthreads();
  if (j >= E) return;
  int d = csr_row_of(off, j, sLo, sHi);
  int sx = eadj[j];  // src*64
  const float4 es = *(const float4*)(esrc + (sx >> 4));
  const float4 ed = *(const float4*)(edst + (size_t)d * 4);
  float q0 = __expf(lrelu(es.x + ed.x));
  float q1 = __expf(lrelu(es.y + ed.y));
  float q2 = __expf(lrelu(es.z + ed.z));
  float q3 = __expf(lrelu(es.w + ed.w));
  qw[j] = make_uint2(bf16pair(q0, q1), bf16pair(q2, q3));
}

// xl = h @ W.T via bf16 MFMA. 128 rows/block, 4 waves (32 rows each), full 128 cols.
// Logits computed with one extra MFMA B-operand (was8), no shuffles.
__global__ __launch_bounds__(256) void gat_xl_kernel(const unsigned short* __restrict__ hb,
                                                     const unsigned short* __restrict__ wb,
                                                     const unsigned short* __restrict__ wasb,
                                                     unsigned int* __restrict__ xlp,
                                                     float* __restrict__ esrc,
                                                     float* __restrict__ edst) {
  __shared__ unsigned short Wl[128][136];  // +8 pad: 2-way bank alias only
  const int tid = threadIdx.x;
  const int lane = tid & 63;
  const int wv = tid >> 6;
  const int base = blockIdx.x * 128;
  const int l15 = lane & 15;
  const int lg = lane >> 4;  // 0..3

  // stage W (bf16) into LDS
#pragma unroll
  for (int t = 0; t < 8; ++t) {
    int f8 = tid + t * 256;          // 2048 chunks of 8 ushorts
    int row = f8 >> 4, c8 = (f8 & 15) * 8;
    uint4 v = *(const uint4*)(wb + row * HID + c8);
    *(uint4*)&Wl[row][c8] = v;
  }
  __syncthreads();

  f32x4 acc[2][8];
  f32x4 acc_e[2];
#pragma unroll
  for (int rb = 0; rb < 2; ++rb) {
#pragma unroll
    for (int nb = 0; nb < 8; ++nb) acc[rb][nb] = (f32x4){0.f, 0.f, 0.f, 0.f};
    acc_e[rb] = (f32x4){0.f, 0.f, 0.f, 0.f};
  }

  int n0 = base + wv * 32 + l15;
  int n1 = n0 + 16;
  if (n0 >= N_NODES) n0 = N_NODES - 1;
  if (n1 >= N_NODES) n1 = N_NODES - 1;
  const size_t rowA0 = (size_t)n0 * HID;
  const size_t rowA1 = (size_t)n1 * HID;

#pragma unroll
  for (int kc = 0; kc < 4; ++kc) {
    const int kb = kc * 32 + lg * 8;
    short8 a0 = *(const short8*)(hb + rowA0 + kb);
    short8 a1 = *(const short8*)(hb + rowA1 + kb);
    short8 efrag = *(const short8*)(wasb + l15 * HID + kb);
    acc_e[0] = __builtin_amdgcn_mfma_f32_16x16x32_bf16(a0, efrag, acc_e[0], 0, 0, 0);
    acc_e[1] = __builtin_amdgcn_mfma_f32_16x16x32_bf16(a1, efrag, acc_e[1], 0, 0, 0);
#pragma unroll
    for (int nb = 0; nb < 8; ++nb) {
      short8 bfrag = *(const short8*)&Wl[nb * 16 + l15][kb];
      acc[0][nb] = __builtin_amdgcn_mfma_f32_16x16x32_bf16(a0, bfrag, acc[0][nb], 0, 0, 0);
      acc[1][nb] = __builtin_amdgcn_mfma_f32_16x16x32_bf16(a1, bfrag, acc[1][nb], 0, 0, 0);
    }
  }

#pragma unroll
  for (int rb = 0; rb < 2; ++rb) {
#pragma unroll
    for (int r = 0; r < 4; ++r) {
      int node = base + wv * 32 + rb * 16 + lg * 4 + r;
      if (node < N_NODES) {
#pragma unroll
        for (int nb = 0; nb < 4; ++nb) {
          unsigned int pk = bf16pair(acc[rb][nb][r], acc[rb][nb + 4][r]);
          xlp[(size_t)node * 64 + nb * 16 + l15] = pk;
        }
        float ev = acc_e[rb][r];
        if (l15 < 4) esrc[node * 4 + l15] = ev;
        else if (l15 < 8) edst[node * 4 + (l15 - 4)] = ev;
      }
    }
  }
}

// single-pass softmax aggregation; per-edge bf16 weights precomputed (qw).
// Wave per node; depth-2 pipelined 4-edge rounds; interleaved LN reduction.
__global__ __launch_bounds__(256) void gat_agg_kernel(const unsigned int* __restrict__ xlp,
                                                      const float* __restrict__ esrc,
                                                      const float* __restrict__ edst,
                                                      const uint2* __restrict__ qw,
                                                      const int* __restrict__ off,
                                                      const int* __restrict__ eadj,
                                                      const float* __restrict__ gbias,
                                                      const float* __restrict__ lng,
                                                      const float* __restrict__ lnb,
                                                      unsigned short* __restrict__ hb) {
  const int tid = threadIdx.x;
  const int lane = tid & 63;
  const int i = blockIdx.x * 4 + (tid >> 6);
  const int hd0 = lane >> 5;

  const float4 ed = *(const float4*)(edst + (size_t)i * 4);
  const float4 e0 = *(const float4*)(esrc + (size_t)i * 4);
  float w0 = __expf(lrelu(e0.x + ed.x));
  float w1 = __expf(lrelu(e0.y + ed.y));
  float w2 = __expf(lrelu(e0.z + ed.z));
  float w3 = __expf(lrelu(e0.w + ed.w));
  float sA = (hd0 == 0 ? w0 : w1);
  float sB = (hd0 == 0 ? w2 : w3);
  const unsigned int* xp = xlp + lane;
  const unsigned int vi = xp[(unsigned)i << 6];
  float accA = bflo(vi) * sA;
  float accB = bfhi(vi) * sB;

  const int beg = off[i], end = off[i + 1];
  int j = beg;
  int4 ea;
  uint2 Qa, Qb, Qc, Qd;
  if (j + 4 <= end) {
    ea = *(const int4*)(eadj + j);
    Qa = qw[j + 0]; Qb = qw[j + 1]; Qc = qw[j + 2]; Qd = qw[j + 3];
  }
  for (; j + 4 <= end;) {
    // issue gathers for current round
    const unsigned int va = xp[(unsigned)ea.x];
    const unsigned int vb = xp[(unsigned)ea.y];
    const unsigned int vc = xp[(unsigned)ea.z];
    const unsigned int vd = xp[(unsigned)ea.w];
    // prefetch next round's contiguous loads
    int4 eaN;
    uint2 QaN, QbN, QcN, QdN;
    const int jn = j + 4;
    const bool more = jn + 4 <= end;
    if (more) {
      eaN = *(const int4*)(eadj + jn);
      QaN = qw[jn + 0]; QbN = qw[jn + 1]; QcN = qw[jn + 2]; QdN = qw[jn + 3];
    }
    float qAa = hd0 == 0 ? bflo(Qa.x) : bfhi(Qa.x);
    float qBa = hd0 == 0 ? bflo(Qa.y) : bfhi(Qa.y);
    float qAb = hd0 == 0 ? bflo(Qb.x) : bfhi(Qb.x);
    float qBb = hd0 == 0 ? bflo(Qb.y) : bfhi(Qb.y);
    float qAc = hd0 == 0 ? bflo(Qc.x) : bfhi(Qc.x);
    float qBc = hd0 == 0 ? bflo(Qc.y) : bfhi(Qc.y);
    float qAd = hd0 == 0 ? bflo(Qd.x) : bfhi(Qd.x);
    float qBd = hd0 == 0 ? bflo(Qd.y) : bfhi(Qd.y);
    sA += qAa + qAb + qAc + qAd;
    sB += qBa + qBb + qBc + qBd;
    accA = fmaf(bflo(va), qAa, accA);
    accA = fmaf(bflo(vb), qAb, accA);
    accA = fmaf(bflo(vc), qAc, accA);
    accA = fmaf(bflo(vd), qAd, accA);
    accB = fmaf(bfhi(va), qBa, accB);
    accB = fmaf(bfhi(vb), qBb, accB);
    accB = fmaf(bfhi(vc), qBc, accB);
    accB = fmaf(bfhi(vd), qBd, accB);
    if (more) { ea = eaN; Qa = QaN; Qb = QbN; Qc = QcN; Qd = QdN; }
    j = jn;
  }
  for (; j < end; ++j) {
    const int sx = eadj[j];
    const uint2 Q = qw[j];
    const unsigned int v = xp[(unsigned)sx];
    float qA = hd0 == 0 ? bflo(Q.x) : bfhi(Q.x);
    float qB = hd0 == 0 ? bflo(Q.y) : bfhi(Q.y);
    sA += qA;
    sB += qB;
    accA = fmaf(bflo(v), qA, accA);
    accB = fmaf(bfhi(v), qB, accB);
  }
  float o0 = accA / (sA + 1e-16f) + gbias[lane];
  float o1 = accB / (sB + 1e-16f) + gbias[lane + 64];
  // interleaved two-moment reduction: mu from s1, var from s2 - mu^2
  float s1 = o0 + o1;
  float s2 = o0 * o0 + o1 * o1;
#pragma unroll
  for (int o = 32; o >= 1; o >>= 1) {
    s1 += __shfl_xor(s1, o, 64);
    s2 += __shfl_xor(s2, o, 64);
  }
  float mu = s1 * (1.f / 128.f);
  float var = fmaxf(s2 * (1.f / 128.f) - mu * mu, 0.f);
  float r = rsqrtf(var + LN_EPS);
  float d0 = o0 - mu, d1 = o1 - mu;
  float hn0 = fmaxf(d0 * r * lng[lane] + lnb[lane], 0.f);
  float hn1 = fmaxf(d1 * r * lng[lane + 64] + lnb[lane + 64], 0.f);
  unsigned short h0 = hb[(size_t)i * HID + lane];
  unsigned short h1 = hb[(size_t)i * HID + 64 + lane];
  float nh0 = __uint_as_float((unsigned int)h0 << 16) + hn0;
  float nh1 = __uint_as_float((unsigned int)h1 << 16) + hn1;
  hb[(size_t)i * HID + lane] = bf16r(nh0);
  hb[(size_t)i * HID + 64 + lane] = bf16r(nh1);
}

__device__ __forceinline__ int lower_bound_dev(const int* a, int n, int v) {
  int lo = 0, hi = n;
  while (lo < hi) {
    int mid = (lo + hi) >> 1;
    if (a[mid] < v) lo = mid + 1; else hi = mid;
  }
  return lo;
}

// per-batch mean pool from bf16 hb; grid (B, 4)
__global__ __launch_bounds__(256) void pool_kernel(const unsigned short* __restrict__ hb,
                                                   const int* __restrict__ batch,
                                                   float* __restrict__ pooled) {
  __shared__ float red[256];
  int b = blockIdx.x, tid = threadIdx.x;
  int start = lower_bound_dev(batch, N_NODES, b);
  int end = lower_bound_dev(batch, N_NODES, b + 1);
  int cl = tid & 31, g = tid >> 5;
  int c = cl + blockIdx.y * 32;
  float acc = 0.f;
  for (int n = start + g; n < end; n += 8)
    acc += __uint_as_float((unsigned int)hb[(size_t)n * HID + c] << 16);
  red[tid] = acc;
  __syncthreads();
  if (g == 0) {
    float tot = 0.f;
#pragma unroll
    for (int k = 0; k < 8; ++k) tot += red[cl + 32 * k];
    float cntf = fmaxf((float)(end - start), 1.f);
    pooled[b * HID + c] = tot / cntf;
  }
}

// One wave per output element (m,c); lane-split K; two independent fused stages.
__global__ __launch_bounds__(256) void gemv2_kernel(
    const float* __restrict__ A1, int lda1, const float* __restrict__ W1,
    const float* __restrict__ b1, float* __restrict__ O1, int ldo1,
    int sh1, int K1, int relu1,
    const float* __restrict__ A2, int lda2, const float* __restrict__ W2,
    const float* __restrict__ b2, float* __restrict__ O2, int ldo2,
    int sh2, int K2, int relu2, int nw1, int nwTot) {
  int gw = (blockIdx.x * 256 + threadIdx.x) >> 6;
  int lane = threadIdx.x & 63;
  if (gw >= nwTot) return;
  const float *A, *W, *b;
  float* O;
  int lda, ldo, K, relu, m, c;
  if (gw < nw1) {
    A = A1; W = W1; b = b1; O = O1; lda = lda1; ldo = ldo1; K = K1; relu = relu1;
    m = gw >> sh1; c = gw & ((1 << sh1) - 1);
  } else {
    int g2 = gw - nw1;
    A = A2; W = W2; b = b2; O = O2; lda = lda2; ldo = ldo2; K = K2; relu = relu2;
    m = g2 >> sh2; c = g2 & ((1 << sh2) - 1);
  }
  const float* a = A + (size_t)m * lda;
  const float* w = W + (size_t)c * K;
  float acc = 0.f;
  for (int k = lane * 2; k < K; k += 128) {
    float2 av = *(const float2*)(a + k);
    float2 wv = *(const float2*)(w + k);
    acc += av.x * wv.x + av.y * wv.y;
  }
  acc = wave_sum64(acc);
  if (lane == 0) {
    acc += b[c];
    if (relu) acc = fmaxf(acc, 0.f);
    O[(size_t)m * ldo + c] = acc;
  }
}

// z1 = relu([att1|att2|seqh|strh] @ p1_W.T + p1_b); wave per (m,c)
__global__ __launch_bounds__(256) void z1_kernel(const float* __restrict__ att1,
                                                 const float* __restrict__ att2,
                                                 const float* __restrict__ seqh,
                                                 const float* __restrict__ strh,
                                                 const float* __restrict__ p1_W,
                                                 const float* __restrict__ p1_b,
                                                 float* __restrict__ z1) {
  int gw = (blockIdx.x * 256 + threadIdx.x) >> 6;
  int lane = threadIdx.x & 63;
  int m = gw >> 8, c = gw & 255;
  const float* segs[4] = {att1 + m * HD, att2 + m * HD, seqh + m * HD, strh + m * HD};
  const float* w = p1_W + (size_t)c * (4 * HD);
  float acc = 0.f;
#pragma unroll
  for (int s = 0; s < 4; ++s) {
    const float* a = segs[s];
#pragma unroll
    for (int k = lane * 2; k < HD; k += 128) {
      float2 av = *(const float2*)(a + k);
      float2 wv = *(const float2*)(w + s * HD + k);
      acc += av.x * wv.x + av.y * wv.y;
    }
  }
  acc = wave_sum64(acc);
  if (lane == 0) z1[m * HD + c] = fmaxf(acc + p1_b[c], 0.f);
}

extern "C" void kernel_launch(void* const* d_in, const int* in_sizes, int n_in,
                              void* d_out, int out_size, void* d_ws, size_t ws_size,
                              hipStream_t stream) {
  const float* seq_emb = (const float*)d_in[0];
  const float* x       = (const float*)d_in[1];
  const int* eidx      = (const int*)d_in[2];
  const int* batch     = (const int*)d_in[3];
  const float* ne_W = (const float*)d_in[4];
  const float* ne_b = (const float*)d_in[5];
  const float* gat_W = (const float*)d_in[6];
  const float* gat_asrc = (const float*)d_in[7];
  const float* gat_adst = (const float*)d_in[8];
  const float* gat_b = (const float*)d_in[9];
  const float* ln_g = (const float*)d_in[10];
  const float* ln_b = (const float*)d_in[11];
  const float* op1_W = (const float*)d_in[12];
  const float* op1_b = (const float*)d_in[13];
  const float* op2_W = (const float*)d_in[14];
  const float* op2_b = (const float*)d_in[15];
  const float* sp_W = (const float*)d_in[16];
  const float* sp_b = (const float*)d_in[17];
  const float* stp_W = (const float*)d_in[18];
  const float* stp_b = (const float*)d_in[19];
  const float* a1_Wi = (const float*)d_in[20];
  const float* a1_bi = (const float*)d_in[21];
  const float* a1_Wo = (const float*)d_in[22];
  const float* a1_bo = (const float*)d_in[23];
  const float* a2_Wi = (const float*)d_in[24];
  const float* a2_bi = (const float*)d_in[25];
  const float* a2_Wo = (const float*)d_in[26];
  const float* a2_bo = (const float*)d_in[27];
  const float* p1_W = (const float*)d_in[28];
  const float* p1_b = (const float*)d_in[29];
  const float* p2_W = (const float*)d_in[30];
  const float* p2_b = (const float*)d_in[31];
  const float* p3_W = (const float*)d_in[32];
  const float* p3_b = (const float*)d_in[33];

  const int E = in_sizes[2] / 2;
  const int* e_src = eidx;
  const int* e_dst = eidx + E;

  char* p = (char*)d_ws;
  auto alloc = [&](size_t bytes) -> void* {
    void* r = p;
    p += (bytes + 255) & ~(size_t)255;
    return r;
  };
  unsigned short* hbuf = (unsigned short*)alloc(sizeof(unsigned short) * (size_t)N_NODES * HID);
  unsigned short* wb   = (unsigned short*)alloc(sizeof(unsigned short) * L_LAYERS * HID * HID);
  unsigned short* was8 = (unsigned short*)alloc(sizeof(unsigned short) * L_LAYERS * 16 * HID);
  unsigned int* xlp = (unsigned int*)alloc(sizeof(unsigned int) * (size_t)N_NODES * 64);
  float* esrc = (float*)alloc(sizeof(float) * (size_t)N_NODES * 4);
  float* edst = (float*)alloc(sizeof(float) * (size_t)N_NODES * 4);
  int* cnt    = (int*)alloc(sizeof(int) * N_NODES);
  int* cur    = (int*)alloc(sizeof(int) * N_NODES);
  int* off    = (int*)alloc(sizeof(int) * (N_NODES + 1));
  int* eadj   = (int*)alloc(sizeof(int) * (size_t)E);
  uint2* qw   = (uint2*)alloc(sizeof(uint2) * (size_t)E);
  int* bsum   = (int*)alloc(sizeof(int) * 128);
  float* pooled = (float*)alloc(sizeof(float) * B_GRAPHS * HID);
  float* t1B   = (float*)alloc(sizeof(float) * B_GRAPHS * HID);
  float* sembB = (float*)alloc(sizeof(float) * B_GRAPHS * HID);
  float* seqhB = (float*)alloc(sizeof(float) * B_GRAPHS * HD);
  float* strhB = (float*)alloc(sizeof(float) * B_GRAPHS * HD);
  float* v1B   = (float*)alloc(sizeof(float) * B_GRAPHS * HD);
  float* v2B   = (float*)alloc(sizeof(float) * B_GRAPHS * HD);
  float* att1B = (float*)alloc(sizeof(float) * B_GRAPHS * HD);
  float* att2B = (float*)alloc(sizeof(float) * B_GRAPHS * HD);
  float* z1B   = (float*)alloc(sizeof(float) * B_GRAPHS * HD);
  float* z2B   = (float*)alloc(sizeof(float) * B_GRAPHS * (HD / 2));

  hipMemsetAsync(cnt, 0, sizeof(int) * N_NODES, stream);
  hipMemsetAsync(cur, 0, sizeof(int) * N_NODES, stream);

  const int SCAN_BLKS = (N_NODES + 1023) / 1024;  // 98
  ne_kernel<<<N_NODES * HID / 256, 256, 0, stream>>>(x, ne_W, ne_b, hbuf);
  wcvt_kernel<<<(L_LAYERS * HID * HID + 255) / 256, 256, 0, stream>>>(gat_W, wb);
  wprep_kernel<<<(L_LAYERS * 16 * 128 + 255) / 256, 256, 0, stream>>>(gat_W, gat_asrc, gat_adst, was8);
  hist_kernel<<<(E + 255) / 256, 256, 0, stream>>>(e_dst, cnt, E);
  scan1_kernel<<<SCAN_BLKS, 1024, 0, stream>>>(cnt, off, bsum, N_NODES);
  scan2_kernel<<<1, 64, 0, stream>>>(bsum, SCAN_BLKS);
  scan3_kernel<<<(N_NODES + 256) / 256, 256, 0, stream>>>(bsum, off, N_NODES, E);
  scatter_kernel<<<(E + 255) / 256, 256, 0, stream>>>(e_src, e_dst, off, cur, eadj, E);

  const unsigned EDGE_BLKS = (E + 255) / 256;
  for (int l = 0; l < L_LAYERS; ++l) {
    gat_xl_kernel<<<(N_NODES + 127) / 128, 256, 0, stream>>>(
        hbuf, wb + (size_t)l * HID * HID, was8 + (size_t)l * 16 * HID,
        xlp, esrc, edst);
    edgew_kernel<<<EDGE_BLKS, 256, 0, stream>>>(eadj, off, esrc, edst, qw, E);
    gat_agg_kernel<<<N_NODES / 4, 256, 0, stream>>>(
        xlp, esrc, edst, qw, off, eadj, gat_b + l * HID, ln_g + l * HID, ln_b + l * HID,
        hbuf);
  }
  pool_kernel<<<dim3(B_GRAPHS, 4), 256, 0, stream>>>(hbuf, batch, pooled);

  // ---- head: 8 dependency levels, wave-per-output ----
  const float* a1_Wv = a1_Wi + 2 * HD * HD;
  const float* a1_bv = a1_bi + 2 * HD;
  const float* a2_Wv = a2_Wi + 2 * HD * HD;
  const float* a2_bv = a2_bi + 2 * HD;
  auto nblk = [](int waves) { return (unsigned)((waves + 3) / 4); };

  {
    int nw1 = B_GRAPHS * HD, nwT = nw1 + B_GRAPHS * HID;
    gemv2_kernel<<<nblk(nwT), 256, 0, stream>>>(
        seq_emb, SEQ_LEN, sp_W, sp_b, seqhB, HD, 8, SEQ_LEN, 0,
        pooled, HID, op1_W, op1_b, t1B, HID, 7, HID, 1, nw1, nwT);
  }
  {
    int nw1 = B_GRAPHS * HD, nwT = nw1 + B_GRAPHS * HID;
    gemv2_kernel<<<nblk(nwT), 256, 0, stream>>>(
        seqhB, HD, a2_Wv, a2_bv, v2B, HD, 8, HD, 0,
        t1B, HID, op2_W, op2_b, sembB, HID, 7, HID, 0, nw1, nwT);
  }
  {
    int nw1 = B_GRAPHS * HD, nwT = nw1 + B_GRAPHS * HD;
    gemv2_kernel<<<nblk(nwT), 256, 0, stream>>>(
        v2B, HD, a2_Wo, a2_bo, att2B, HD, 8, HD, 0,
        sembB, HID, stp_W, stp_b, strhB, HD, 8, HID, 0, nw1, nwT);
  }
  {
    int nwT = B_GRAPHS * HD;
    gemv2_kernel<<<nblk(nwT), 256, 0, stream>>>(
        strhB, HD, a1_Wv, a1_bv, v1B, HD, 8, HD, 0,
        nullptr, 0, nullptr, nullptr, nullptr, 0, 0, 0, 0, nwT, nwT);
  }
  {
    int nwT = B_GRAPHS * HD;
    gemv2_kernel<<<nblk(nwT), 256, 0, stream>>>(
        v1B, HD, a1_Wo, a1_bo, att1B, HD, 8, HD, 0,
        nullptr, 0, nullptr, nullptr, nullptr, 0, 0, 0, 0, nwT, nwT);
  }
  z1_kernel<<<nblk(B_GRAPHS * HD), 256, 0, stream>>>(att1B, att2B, seqhB, strhB, p1_W, p1_b, z1B);
  {
    int nwT = B_GRAPHS * (HD / 2);
    gemv2_kernel<<<nblk(nwT), 256, 0, stream>>>(
        z1B, HD, p2_W, p2_b, z2B, HD / 2, 7, HD, 1,
        nullptr, 0, nullptr, nullptr, nullptr, 0, 0, 0, 0, nwT, nwT);
  }
  {
    int nwT = B_GRAPHS;
    gemv2_kernel<<<nblk(nwT), 256, 0, stream>>>(
        z2B, HD / 2, p3_W, p3_b, (float*)d_out, 1, 0, HD / 2, 0,
        nullptr, 0, nullptr, nullptr, nullptr, 0, 0, 0, 0, nwT, nwT);
  }
}